// Round 7
// baseline (220.966 us; speedup 1.0000x reference)
//
#include <hip/hip_runtime.h>

// SelfAttention (SAGAN-style) on MI355X.
// B=2, C=64, C8=8, H=W=96, N=9216.  out = gamma * Attn(g,f,h) + x
//   K = f = (Wq/sq) x + bq   (pre-scaled by log2e; softmax in exp2 domain)
//   Q = g = (Wk/sk) x + bk
//   V = h = (Wv/sv) x + bv
// softmax over keys i; head_dim 8 (zero-padded to MFMA K=32), dv=64.
//
// R7: barrier-free K-loop. R6 pathology: per-round __syncthreads (needed to
// publish P and V across waves) forces vmcnt(0) drain of the just-issued
// prefetch -> ~1500 cyc/round stall at 2.25 blocks/CU. Now wave w owns key
// chunk (4r+w)*32 end-to-end: S (4 MFMAs) -> exp2 -> P transpose through the
// wave's PRIVATE LDS slice (same-wave DS ordering, no barrier) -> PV over all
// 64 channels (8 MFMAs) with V as plain b128 register B-frags. O merged across
// waves ONCE at the end (stride-33 LDS, conflict-free). All K/V buffers are
// individually named scalars inside macros: R1/R5 scratch disasters were SROA
// failing on arrays-passed-by-reference, not allocator pressure.
// Numerics identical to R5/R6 (M = |Q|*max|K'| - 12, f16 P, f16-rounded l).

#define N_PIX 9216
#define N_B   2
#define N_C   64

typedef _Float16 half8  __attribute__((ext_vector_type(8)));
typedef _Float16 half4v __attribute__((ext_vector_type(4)));
typedef float    float4v __attribute__((ext_vector_type(4)));

#define LOG2E 1.44269504088896340736f
#define EXP_SHIFT 12.0f

// ---------------------------------------------------------------- k_sigma
__global__ __launch_bounds__(64) void k_sigma(const float* __restrict__ Wq,
                                              const float* __restrict__ Wk,
                                              const float* __restrict__ Wv,
                                              float* __restrict__ sig) {
  __shared__ float G8[8][8];
  __shared__ float Wl[64 * 64];
  __shared__ _Float16 Wh[64 * 80];
  __shared__ _Float16 Gh[64 * 80];
  const int t = threadIdx.x;
  const int mat = blockIdx.x;
  if (mat < 2) {
    const float* W = (mat == 0) ? Wq : Wk;
    const int i = t >> 3, j = t & 7;
    float g = 0.f;
    for (int c = 0; c < 64; ++c) g += W[i * 64 + c] * W[j * 64 + c];
    G8[i][j] = g;
    __syncthreads();
    const int L = t & 7;
    float G0[8], Gr[8];
    for (int k = 0; k < 8; ++k) { G0[k] = G8[L][k]; Gr[k] = G0[k]; }
    for (int it = 0; it < 8; ++it) {
      float g2[8] = {0, 0, 0, 0, 0, 0, 0, 0};
      for (int k = 0; k < 8; ++k) {
        float gik = Gr[k];
        for (int jj = 0; jj < 8; ++jj) g2[jj] += gik * __shfl(Gr[jj], k, 64);
      }
      float mx = 0.f;
      for (int jj = 0; jj < 8; ++jj) mx = fmaxf(mx, fabsf(g2[jj]));
      for (int d = 1; d < 8; d <<= 1) mx = fmaxf(mx, __shfl_xor(mx, d, 64));
      float r = 1.f / mx;
      for (int jj = 0; jj < 8; ++jj) Gr[jj] = g2[jj] * r;
    }
    float u = 0.f;
    for (int jj = 0; jj < 8; ++jj) u += Gr[jj];
    float y = 0.f;
    for (int k = 0; k < 8; ++k) y += G0[k] * __shfl(u, k, 64);
    float nu = u * y, de = u * u;
    for (int d = 1; d < 8; d <<= 1) { nu += __shfl_xor(nu, d, 64); de += __shfl_xor(de, d, 64); }
    if (t == 0) sig[mat] = sqrtf(nu / de);
  } else {
    for (int idx = t; idx < 4096; idx += 64) Wl[idx] = Wv[idx];
    __syncthreads();
    for (int idx = t; idx < 4096; idx += 64) Wh[(idx >> 6) * 80 + (idx & 63)] = (_Float16)Wl[idx];
    __syncthreads();
    const int lane15 = t & 15, quad = t >> 4;
    half8 fr[4][2];
    for (int rb = 0; rb < 4; ++rb)
      for (int kc = 0; kc < 2; ++kc)
        fr[rb][kc] = *(const half8*)&Wh[(lane15 + 16 * rb) * 80 + 32 * kc + 8 * quad];
    float4v D[4][4];
    for (int mb = 0; mb < 4; ++mb) for (int nb = 0; nb < 4; ++nb) D[mb][nb] = (float4v){0.f, 0.f, 0.f, 0.f};
    for (int kc = 0; kc < 2; ++kc)
      for (int mb = 0; mb < 4; ++mb)
        for (int nb = 0; nb < 4; ++nb)
          D[mb][nb] = __builtin_amdgcn_mfma_f32_16x16x32_f16(fr[mb][kc], fr[nb][kc], D[mb][nb], 0, 0, 0);
    for (int it = 0; it < 8; ++it) {
      float mx = 0.f;
      for (int mb = 0; mb < 4; ++mb) for (int nb = 0; nb < 4; ++nb) for (int r = 0; r < 4; ++r)
        mx = fmaxf(mx, fabsf(D[mb][nb][r]));
      for (int d = 1; d < 64; d <<= 1) mx = fmaxf(mx, __shfl_xor(mx, d, 64));
      float rs = 1.f / mx;
      for (int mb = 0; mb < 4; ++mb) for (int nb = 0; nb < 4; ++nb) for (int r = 0; r < 4; ++r)
        Gh[(4 * quad + r + 16 * mb) * 80 + lane15 + 16 * nb] = (_Float16)(D[mb][nb][r] * rs);
      __syncthreads();
      if (it == 7) break;
      for (int rb = 0; rb < 4; ++rb)
        for (int kc = 0; kc < 2; ++kc)
          fr[rb][kc] = *(const half8*)&Gh[(lane15 + 16 * rb) * 80 + 32 * kc + 8 * quad];
      for (int mb = 0; mb < 4; ++mb) for (int nb = 0; nb < 4; ++nb) D[mb][nb] = (float4v){0.f, 0.f, 0.f, 0.f};
      for (int kc = 0; kc < 2; ++kc)
        for (int mb = 0; mb < 4; ++mb)
          for (int nb = 0; nb < 4; ++nb)
            D[mb][nb] = __builtin_amdgcn_mfma_f32_16x16x32_f16(fr[mb][kc], fr[nb][kc], D[mb][nb], 0, 0, 0);
      __syncthreads();
    }
    float u = 0.f;
    for (int c = 0; c < 64; ++c) u += (float)Gh[t * 80 + c];
    float z = 0.f;
    for (int i2 = 0; i2 < 64; ++i2) z += Wl[i2 * 64 + t] * __shfl(u, i2, 64);
    float nu = z * z, de = u * u;
    for (int d = 1; d < 64; d <<= 1) { nu += __shfl_xor(nu, d, 64); de += __shfl_xor(de, d, 64); }
    if (t == 0) sig[2] = sqrtf(nu / de);
  }
}

// ---------------------------------------------------------------- k_wconv
__global__ __launch_bounds__(128) void k_wconv(const float* __restrict__ Wq, const float* __restrict__ bq,
                                               const float* __restrict__ Wk, const float* __restrict__ bk,
                                               const float* __restrict__ Wv, const float* __restrict__ bv,
                                               const float* __restrict__ sig,
                                               _Float16* __restrict__ W16, float* __restrict__ b80,
                                               unsigned* __restrict__ maxKu) {
  const float iq = LOG2E / sig[0], ik = 1.0f / sig[1], iv = 1.0f / sig[2];
  const int t = threadIdx.x;
  for (int idx = t; idx < 80 * 64; idx += 128) {
    const int m = idx >> 6, c = idx & 63;
    float v;
    if (m < 8)       v = Wq[m * 64 + c] * iq;
    else if (m < 16) v = Wk[(m - 8) * 64 + c] * ik;
    else             v = Wv[(m - 16) * 64 + c] * iv;
    W16[idx] = (_Float16)v;
  }
  if (t < 80) {
    float v;
    if (t < 8)       v = bq[t] * LOG2E;
    else if (t < 16) v = bk[t - 8];
    else             v = bv[t - 16];
    b80[t] = v;
  }
  if (t < 2) maxKu[t] = 0u;
}

// ---------------------------------------------------------------- k_fgh
__global__ __launch_bounds__(256) void k_fgh(const float* __restrict__ x,
                                             const _Float16* __restrict__ W16,
                                             const float* __restrict__ b80,
                                             _Float16* __restrict__ K16,
                                             _Float16* __restrict__ Q16,
                                             _Float16* __restrict__ VT16,
                                             unsigned* __restrict__ maxKu) {
  const int wave = threadIdx.x >> 6;
  const int lane = threadIdx.x & 63;
  const int lane15 = lane & 15, quad = lane >> 4;
  const int tile = blockIdx.x * 4 + wave;
  const int b = tile / 576;
  const int n = (tile % 576) * 16 + lane15;
  half8 wf[5][2];
  for (int mb = 0; mb < 5; ++mb)
    for (int kc = 0; kc < 2; ++kc)
      wf[mb][kc] = *(const half8*)&W16[(lane15 + 16 * mb) * 64 + 32 * kc + 8 * quad];
  float4v acc[5];
  for (int mb = 0; mb < 5; ++mb) acc[mb] = *(const float4v*)&b80[16 * mb + 4 * quad];
  const float* xb = x + (size_t)b * N_C * N_PIX;
  for (int kc = 0; kc < 2; ++kc) {
    half8 bf;
    for (int j = 0; j < 8; ++j)
      bf[j] = (_Float16)xb[(size_t)(32 * kc + 8 * quad + j) * N_PIX + n];
    for (int mb = 0; mb < 5; ++mb)
      acc[mb] = __builtin_amdgcn_mfma_f32_16x16x32_f16(wf[mb][kc], bf, acc[mb], 0, 0, 0);
  }
  {
    _Float16* dstK = K16 + ((size_t)b * N_PIX + n) * 8;
    _Float16* dstQ = Q16 + ((size_t)b * N_PIX + n) * 8;
    for (int r = 0; r < 4; ++r) {
      const int m = 4 * quad + r;
      const _Float16 v = (_Float16)acc[0][r];
      if (m < 8) dstK[m] = v; else dstQ[m - 8] = v;
    }
  }
  for (int mb = 1; mb < 5; ++mb)
    for (int r = 0; r < 4; ++r) {
      const int c = 4 * quad + r + 16 * (mb - 1);
      VT16[((size_t)b * N_C + c) * N_PIX + n] = (_Float16)acc[mb][r];
    }
  float sq = 0.f;
  if (quad < 2)
    for (int r = 0; r < 4; ++r) sq += acc[0][r] * acc[0][r];
  sq += __shfl_xor(sq, 16, 64);
  for (int d = 1; d < 64; d <<= 1) sq = fmaxf(sq, __shfl_xor(sq, d, 64));
  if (lane == 0) atomicMax(&maxKu[b], __float_as_uint(sq));
}

// ---------------------------------------------------------------- k_attn
// 576 blocks x 4 waves, 32-query tile. Round r: wave w owns keys
// [(4r+w)*32, +32). Per round (no barriers):
//   4 S-MFMAs (2 key-halves x 2 query-groups) -> exp2 -> P transpose through
//   the wave's private LDS slice -> 8 PV MFMAs (2 groups x 4 channel blocks).
// End: one __syncthreads + O/l merge across waves (key-split partials).

__global__ __launch_bounds__(256, 2) void k_attn(const _Float16* __restrict__ K16,
                                                 const _Float16* __restrict__ Q16,
                                                 const _Float16* __restrict__ VT16,
                                                 const unsigned* __restrict__ maxKu,
                                                 const float* __restrict__ x,
                                                 const float* __restrict__ gamma,
                                                 float* __restrict__ out) {
  __shared__ __align__(16) _Float16 P_lds[4][32 * 40];  // per-wave slice, 40-half rows
  __shared__ float Lsh[4][32];
  __shared__ float Osh[4][64][33];                      // stride 33: conflict-free
  const int wave = threadIdx.x >> 6;
  const int lane = threadIdx.x & 63;
  const int lane15 = lane & 15, quad = lane >> 4;
  const int tile = blockIdx.x;            // 0..575
  const int b = tile / 288;
  const int jb = (tile % 288) * 32;
  const float gm = gamma[0];
  const _Float16* Kb = K16 + (size_t)b * N_PIX * 8;
  const _Float16* Vb = VT16 + (size_t)b * N_C * N_PIX;
  _Float16* Pl = P_lds[wave];
  // V B-frag base pointers: channel c = lane15 + 16*cb, key offset 8*quad.
  const _Float16* pV0 = Vb + (size_t)(lane15) * N_PIX + 8 * quad;
  const _Float16* pV1 = Vb + (size_t)(lane15 + 16) * N_PIX + 8 * quad;
  const _Float16* pV2 = Vb + (size_t)(lane15 + 32) * N_PIX + 8 * quad;
  const _Float16* pV3 = Vb + (size_t)(lane15 + 48) * N_PIX + 8 * quad;

  // Q frags (B-operand): quad0 holds Q[query][k=0..7]; other quads zero.
  half8 qf0 = {}, qf1 = {};
  if (quad == 0) {
    qf0 = *(const half8*)(Q16 + ((size_t)b * N_PIX + jb + lane15) * 8);
    qf1 = *(const half8*)(Q16 + ((size_t)b * N_PIX + jb + 16 + lane15) * 8);
  }
  // bound-max per query (R5 numerics)
  const float maxK = sqrtf(__uint_as_float(maxKu[b]));
  float nq0 = 0.f, nq1 = 0.f;
  if (quad == 0)
#pragma unroll
    for (int j = 0; j < 8; ++j) {
      nq0 += (float)qf0[j] * (float)qf0[j];
      nq1 += (float)qf1[j] * (float)qf1[j];
    }
  nq0 = __shfl(nq0, lane15, 64);
  nq1 = __shfl(nq1, lane15, 64);
  const float M0 = sqrtf(nq0) * maxK - EXP_SHIFT;
  const float M1 = sqrtf(nq1) * maxK - EXP_SHIFT;

  float4v a00 = {0.f,0.f,0.f,0.f}, a01 = {0.f,0.f,0.f,0.f}, a02 = {0.f,0.f,0.f,0.f}, a03 = {0.f,0.f,0.f,0.f};
  float4v a10 = {0.f,0.f,0.f,0.f}, a11 = {0.f,0.f,0.f,0.f}, a12 = {0.f,0.f,0.f,0.f}, a13 = {0.f,0.f,0.f,0.f};
  float ls0 = 0.f, ls1 = 0.f;
  const float4v f4z = {0.f, 0.f, 0.f, 0.f};

  // named double buffers (scalars only -> SROA-proof)
  half8 kA0 = {}, kA1 = {}, kB0 = {}, kB1 = {};
  half8 vA0, vA1, vA2, vA3, vB0, vB1, vB2, vB3;

#define LOADK(K0, K1, I)                                                \
  if (quad == 0) {                                                      \
    K0 = *(const half8*)(Kb + (size_t)((I) + lane15) * 8);              \
    K1 = *(const half8*)(Kb + (size_t)((I) + 16 + lane15) * 8);         \
  }
#define LOADV(V0, V1, V2, V3, I)                                        \
  V0 = *(const half8*)(pV0 + (I));                                      \
  V1 = *(const half8*)(pV1 + (I));                                      \
  V2 = *(const half8*)(pV2 + (I));                                      \
  V3 = *(const half8*)(pV3 + (I));

  const int base = 32 * wave;
  LOADK(kA0, kA1, base)
  LOADV(vA0, vA1, vA2, vA3, base)

#define ROUND(KF0, KF1, VF0, VF1, VF2, VF3, KN0, KN1, VN0, VN1, VN2, VN3, PI, PREF) \
  {                                                                                 \
    if (PREF) { LOADK(KN0, KN1, PI) LOADV(VN0, VN1, VN2, VN3, PI) }                 \
    float4v s00 = __builtin_amdgcn_mfma_f32_16x16x32_f16(KF0, qf0, f4z, 0, 0, 0);   \
    float4v s01 = __builtin_amdgcn_mfma_f32_16x16x32_f16(KF0, qf1, f4z, 0, 0, 0);   \
    float4v s10 = __builtin_amdgcn_mfma_f32_16x16x32_f16(KF1, qf0, f4z, 0, 0, 0);   \
    float4v s11 = __builtin_amdgcn_mfma_f32_16x16x32_f16(KF1, qf1, f4z, 0, 0, 0);   \
    half4v h00, h01, h10, h11;                                                      \
    _Pragma("unroll") for (int r = 0; r < 4; ++r) {                                 \
      const float p00 = __builtin_amdgcn_exp2f(s00[r] - M0);                        \
      const float p01 = __builtin_amdgcn_exp2f(s01[r] - M1);                        \
      const float p10 = __builtin_amdgcn_exp2f(s10[r] - M0);                        \
      const float p11 = __builtin_amdgcn_exp2f(s11[r] - M1);                        \
      h00[r] = (_Float16)p00; ls0 += (float)h00[r];                                 \
      h01[r] = (_Float16)p01; ls1 += (float)h01[r];                                 \
      h10[r] = (_Float16)p10; ls0 += (float)h10[r];                                 \
      h11[r] = (_Float16)p11; ls1 += (float)h11[r];                                 \
    }                                                                               \
    *(half4v*)&Pl[lane15 * 40 + 4 * quad] = h00;                                    \
    *(half4v*)&Pl[lane15 * 40 + 16 + 4 * quad] = h10;                               \
    *(half4v*)&Pl[(16 + lane15) * 40 + 4 * quad] = h01;                             \
    *(half4v*)&Pl[(16 + lane15) * 40 + 16 + 4 * quad] = h11;                        \
    const half8 pf0 = *(const half8*)&Pl[lane15 * 40 + 8 * quad];                   \
    const half8 pf1 = *(const half8*)&Pl[(16 + lane15) * 40 + 8 * quad];            \
    a00 = __builtin_amdgcn_mfma_f32_16x16x32_f16(pf0, VF0, a00, 0, 0, 0);           \
    a01 = __builtin_amdgcn_mfma_f32_16x16x32_f16(pf0, VF1, a01, 0, 0, 0);           \
    a02 = __builtin_amdgcn_mfma_f32_16x16x32_f16(pf0, VF2, a02, 0, 0, 0);           \
    a03 = __builtin_amdgcn_mfma_f32_16x16x32_f16(pf0, VF3, a03, 0, 0, 0);           \
    a10 = __builtin_amdgcn_mfma_f32_16x16x32_f16(pf1, VF0, a10, 0, 0, 0);           \
    a11 = __builtin_amdgcn_mfma_f32_16x16x32_f16(pf1, VF1, a11, 0, 0, 0);           \
    a12 = __builtin_amdgcn_mfma_f32_16x16x32_f16(pf1, VF2, a12, 0, 0, 0);           \
    a13 = __builtin_amdgcn_mfma_f32_16x16x32_f16(pf1, VF3, a13, 0, 0, 0);           \
  }

#pragma unroll 1
  for (int j = 0; j < 36; ++j) {                    // 72 rounds, 2 per iter
    const int i0 = 256 * j + base;
    ROUND(kA0, kA1, vA0, vA1, vA2, vA3, kB0, kB1, vB0, vB1, vB2, vB3, i0 + 128, true)
    ROUND(kB0, kB1, vB0, vB1, vB2, vB3, kA0, kA1, vA0, vA1, vA2, vA3, i0 + 256, j < 35)
  }
#undef ROUND
#undef LOADK
#undef LOADV

  // ---- merge across waves (key-split partials); one barrier total.
  ls0 += __shfl_xor(ls0, 16, 64); ls0 += __shfl_xor(ls0, 32, 64);
  ls1 += __shfl_xor(ls1, 16, 64); ls1 += __shfl_xor(ls1, 32, 64);
  if (quad == 0) { Lsh[wave][lane15] = ls0; Lsh[wave][16 + lane15] = ls1; }
#pragma unroll
  for (int r = 0; r < 4; ++r) {
    Osh[wave][lane][r]      = a00[r];
    Osh[wave][lane][4 + r]  = a01[r];
    Osh[wave][lane][8 + r]  = a02[r];
    Osh[wave][lane][12 + r] = a03[r];
    Osh[wave][lane][16 + r] = a10[r];
    Osh[wave][lane][20 + r] = a11[r];
    Osh[wave][lane][24 + r] = a12[r];
    Osh[wave][lane][28 + r] = a13[r];
  }
  __syncthreads();
  float4v lt0 = {0.f, 0.f, 0.f, 0.f}, lt1 = {0.f, 0.f, 0.f, 0.f};
#pragma unroll
  for (int w = 0; w < 4; ++w) {
    const float4v a = *(const float4v*)&Lsh[w][4 * quad];
    const float4v c = *(const float4v*)&Lsh[w][16 + 4 * quad];
#pragma unroll
    for (int r = 0; r < 4; ++r) { lt0[r] += a[r]; lt1[r] += c[r]; }
  }
  // this thread emits channels ch = 16*wave + lane15 (cb = wave)
  float4v o0 = {0.f, 0.f, 0.f, 0.f}, o1 = {0.f, 0.f, 0.f, 0.f};
#pragma unroll
  for (int w = 0; w < 4; ++w)
#pragma unroll
    for (int r = 0; r < 4; ++r) {
      o0[r] += Osh[w][lane][4 * wave + r];
      o1[r] += Osh[w][lane][16 + 4 * wave + r];
    }
  const int ch = 16 * wave + lane15;
  const float* xb = x + (size_t)b * N_C * N_PIX;
  float* ob = out + (size_t)b * N_C * N_PIX;
  {
    const size_t idx = (size_t)ch * N_PIX + jb + 4 * quad;
    const float4v xr = *(const float4v*)(xb + idx);
    float4v o;
#pragma unroll
    for (int r = 0; r < 4; ++r) o[r] = gm * o0[r] / lt0[r] + xr[r];
    *(float4v*)(ob + idx) = o;
  }
  {
    const size_t idx = (size_t)ch * N_PIX + jb + 16 + 4 * quad;
    const float4v xr = *(const float4v*)(xb + idx);
    float4v o;
#pragma unroll
    for (int r = 0; r < 4; ++r) o[r] = gm * o1[r] / lt1[r] + xr[r];
    *(float4v*)(ob + idx) = o;
  }
}

// ---------------------------------------------------------------- launch
extern "C" void kernel_launch(void* const* d_in, const int* in_sizes, int n_in,
                              void* d_out, int out_size, void* d_ws, size_t ws_size,
                              hipStream_t stream) {
  const float* x     = (const float*)d_in[0];
  const float* Wq    = (const float*)d_in[1];
  const float* bq    = (const float*)d_in[2];
  const float* Wk    = (const float*)d_in[3];
  const float* bk    = (const float*)d_in[4];
  const float* Wv    = (const float*)d_in[5];
  const float* bv    = (const float*)d_in[6];
  const float* gamma = (const float*)d_in[7];
  float* out = (float*)d_out;

  char* ws = (char*)d_ws;
  float*    sig   = (float*)ws;                       // 4 floats
  unsigned* maxKu = (unsigned*)(ws + 16);             // 2 uints (float bits, >=0)
  float*    b80   = (float*)(ws + 32);                // 80 floats
  _Float16* W16   = (_Float16*)(ws + 512);            // 80*64 halves
  _Float16* K16   = (_Float16*)(ws + 10752);          // 2*9216*8
  _Float16* Q16   = (_Float16*)(ws + 10752 + 294912); // 2*9216*8
  _Float16* VT16  = (_Float16*)(ws + 10752 + 2 * 294912); // 2*64*9216

  hipLaunchKernelGGL(k_sigma, dim3(3), dim3(64), 0, stream, Wq, Wk, Wv, sig);
  hipLaunchKernelGGL(k_wconv, dim3(1), dim3(128), 0, stream, Wq, bq, Wk, bk, Wv, bv, sig, W16, b80, maxKu);
  hipLaunchKernelGGL(k_fgh, dim3(288), dim3(256), 0, stream, x, W16, b80, K16, Q16, VT16, maxKu);
  hipLaunchKernelGGL(k_attn, dim3(576), dim3(256), 0, stream, K16, Q16, VT16, maxKu, x, gamma, out);
}

// Round 9
// 198.027 us; speedup vs baseline: 1.1158x; 1.1158x over previous
//
#include <hip/hip_runtime.h>

// SelfAttention (SAGAN-style) on MI355X.
// B=2, C=64, C8=8, H=W=96, N=9216.  out = gamma * Attn(g,f,h) + x
//   K = f = (Wq/sq) x + bq   (pre-scaled by log2e; softmax in exp2 domain)
//   Q = g = (Wk/sk) x + bk
//   V = h = (Wv/sv) x + bv
// softmax over keys i; head_dim 8 (zero-padded to MFMA K=32), dv=64.
//
// R9: barrier-free K-loop + LDS staging + manual waitcnt.
//  - R6 (101us) lost ~20% to per-round __syncthreads vmcnt(0) drains.
//  - R7/R5/R1: register prefetch buffers always lose (SROA/spill/sinking).
//  - R8: asm register loads + tied waits -> crash.
// Now: wave w owns key chunk (4r+w)*32 end-to-end (K,V,P all same-wave ->
// ZERO barriers in the loop). K and V staged to per-wave LDS slots with
// global_load_lds (placement pinned), double-buffered, 1-round lookahead;
// readiness via a bare `s_waitcnt vmcnt(5)` (only vmcnt traffic is ours).
// LDS->reg via single asm blocks "ds_read_b128 xN; s_waitcnt lgkmcnt(0)"
// (self-contained: no ties needed). P transpose stays same-wave-private.
// O merged across waves once at the end (two-phase 17KB Osh).
// Numerics unchanged (M = |Q|*max|K'| - 12, f16 P, f16-rounded lsum).

#define N_PIX 9216
#define N_B   2
#define N_C   64

typedef _Float16 half8  __attribute__((ext_vector_type(8)));
typedef _Float16 half4v __attribute__((ext_vector_type(4)));
typedef float    float4v __attribute__((ext_vector_type(4)));
typedef int      int4v  __attribute__((ext_vector_type(4)));

#define LOG2E 1.44269504088896340736f
#define EXP_SHIFT 12.0f

// ---------------------------------------------------------------- k_sigma
__global__ __launch_bounds__(64) void k_sigma(const float* __restrict__ Wq,
                                              const float* __restrict__ Wk,
                                              const float* __restrict__ Wv,
                                              float* __restrict__ sig) {
  __shared__ float G8[8][8];
  __shared__ float Wl[64 * 64];
  __shared__ _Float16 Wh[64 * 80];
  __shared__ _Float16 Gh[64 * 80];
  const int t = threadIdx.x;
  const int mat = blockIdx.x;
  if (mat < 2) {
    const float* W = (mat == 0) ? Wq : Wk;
    const int i = t >> 3, j = t & 7;
    float g = 0.f;
    for (int c = 0; c < 64; ++c) g += W[i * 64 + c] * W[j * 64 + c];
    G8[i][j] = g;
    __syncthreads();
    const int L = t & 7;
    float G0[8], Gr[8];
    for (int k = 0; k < 8; ++k) { G0[k] = G8[L][k]; Gr[k] = G0[k]; }
    for (int it = 0; it < 8; ++it) {
      float g2[8] = {0, 0, 0, 0, 0, 0, 0, 0};
      for (int k = 0; k < 8; ++k) {
        float gik = Gr[k];
        for (int jj = 0; jj < 8; ++jj) g2[jj] += gik * __shfl(Gr[jj], k, 64);
      }
      float mx = 0.f;
      for (int jj = 0; jj < 8; ++jj) mx = fmaxf(mx, fabsf(g2[jj]));
      for (int d = 1; d < 8; d <<= 1) mx = fmaxf(mx, __shfl_xor(mx, d, 64));
      float r = 1.f / mx;
      for (int jj = 0; jj < 8; ++jj) Gr[jj] = g2[jj] * r;
    }
    float u = 0.f;
    for (int jj = 0; jj < 8; ++jj) u += Gr[jj];
    float y = 0.f;
    for (int k = 0; k < 8; ++k) y += G0[k] * __shfl(u, k, 64);
    float nu = u * y, de = u * u;
    for (int d = 1; d < 8; d <<= 1) { nu += __shfl_xor(nu, d, 64); de += __shfl_xor(de, d, 64); }
    if (t == 0) sig[mat] = sqrtf(nu / de);
  } else {
    for (int idx = t; idx < 4096; idx += 64) Wl[idx] = Wv[idx];
    __syncthreads();
    for (int idx = t; idx < 4096; idx += 64) Wh[(idx >> 6) * 80 + (idx & 63)] = (_Float16)Wl[idx];
    __syncthreads();
    const int lane15 = t & 15, quad = t >> 4;
    half8 fr[4][2];
    for (int rb = 0; rb < 4; ++rb)
      for (int kc = 0; kc < 2; ++kc)
        fr[rb][kc] = *(const half8*)&Wh[(lane15 + 16 * rb) * 80 + 32 * kc + 8 * quad];
    float4v D[4][4];
    for (int mb = 0; mb < 4; ++mb) for (int nb = 0; nb < 4; ++nb) D[mb][nb] = (float4v){0.f, 0.f, 0.f, 0.f};
    for (int kc = 0; kc < 2; ++kc)
      for (int mb = 0; mb < 4; ++mb)
        for (int nb = 0; nb < 4; ++nb)
          D[mb][nb] = __builtin_amdgcn_mfma_f32_16x16x32_f16(fr[mb][kc], fr[nb][kc], D[mb][nb], 0, 0, 0);
    for (int it = 0; it < 8; ++it) {
      float mx = 0.f;
      for (int mb = 0; mb < 4; ++mb) for (int nb = 0; nb < 4; ++nb) for (int r = 0; r < 4; ++r)
        mx = fmaxf(mx, fabsf(D[mb][nb][r]));
      for (int d = 1; d < 64; d <<= 1) mx = fmaxf(mx, __shfl_xor(mx, d, 64));
      float rs = 1.f / mx;
      for (int mb = 0; mb < 4; ++mb) for (int nb = 0; nb < 4; ++nb) for (int r = 0; r < 4; ++r)
        Gh[(4 * quad + r + 16 * mb) * 80 + lane15 + 16 * nb] = (_Float16)(D[mb][nb][r] * rs);
      __syncthreads();
      if (it == 7) break;
      for (int rb = 0; rb < 4; ++rb)
        for (int kc = 0; kc < 2; ++kc)
          fr[rb][kc] = *(const half8*)&Gh[(lane15 + 16 * rb) * 80 + 32 * kc + 8 * quad];
      for (int mb = 0; mb < 4; ++mb) for (int nb = 0; nb < 4; ++nb) D[mb][nb] = (float4v){0.f, 0.f, 0.f, 0.f};
      for (int kc = 0; kc < 2; ++kc)
        for (int mb = 0; mb < 4; ++mb)
          for (int nb = 0; nb < 4; ++nb)
            D[mb][nb] = __builtin_amdgcn_mfma_f32_16x16x32_f16(fr[mb][kc], fr[nb][kc], D[mb][nb], 0, 0, 0);
      __syncthreads();
    }
    float u = 0.f;
    for (int c = 0; c < 64; ++c) u += (float)Gh[t * 80 + c];
    float z = 0.f;
    for (int i2 = 0; i2 < 64; ++i2) z += Wl[i2 * 64 + t] * __shfl(u, i2, 64);
    float nu = z * z, de = u * u;
    for (int d = 1; d < 64; d <<= 1) { nu += __shfl_xor(nu, d, 64); de += __shfl_xor(de, d, 64); }
    if (t == 0) sig[2] = sqrtf(nu / de);
  }
}

// ---------------------------------------------------------------- k_wconv
__global__ __launch_bounds__(128) void k_wconv(const float* __restrict__ Wq, const float* __restrict__ bq,
                                               const float* __restrict__ Wk, const float* __restrict__ bk,
                                               const float* __restrict__ Wv, const float* __restrict__ bv,
                                               const float* __restrict__ sig,
                                               _Float16* __restrict__ W16, float* __restrict__ b80,
                                               unsigned* __restrict__ maxKu) {
  const float iq = LOG2E / sig[0], ik = 1.0f / sig[1], iv = 1.0f / sig[2];
  const int t = threadIdx.x;
  for (int idx = t; idx < 80 * 64; idx += 128) {
    const int m = idx >> 6, c = idx & 63;
    float v;
    if (m < 8)       v = Wq[m * 64 + c] * iq;
    else if (m < 16) v = Wk[(m - 8) * 64 + c] * ik;
    else             v = Wv[(m - 16) * 64 + c] * iv;
    W16[idx] = (_Float16)v;
  }
  if (t < 80) {
    float v;
    if (t < 8)       v = bq[t] * LOG2E;
    else if (t < 16) v = bk[t - 8];
    else             v = bv[t - 16];
    b80[t] = v;
  }
  if (t < 2) maxKu[t] = 0u;
}

// ---------------------------------------------------------------- k_fgh
__global__ __launch_bounds__(256) void k_fgh(const float* __restrict__ x,
                                             const _Float16* __restrict__ W16,
                                             const float* __restrict__ b80,
                                             _Float16* __restrict__ K16,
                                             _Float16* __restrict__ Q16,
                                             _Float16* __restrict__ VT16,
                                             unsigned* __restrict__ maxKu) {
  const int wave = threadIdx.x >> 6;
  const int lane = threadIdx.x & 63;
  const int lane15 = lane & 15, quad = lane >> 4;
  const int tile = blockIdx.x * 4 + wave;
  const int b = tile / 576;
  const int n = (tile % 576) * 16 + lane15;
  half8 wf[5][2];
  for (int mb = 0; mb < 5; ++mb)
    for (int kc = 0; kc < 2; ++kc)
      wf[mb][kc] = *(const half8*)&W16[(lane15 + 16 * mb) * 64 + 32 * kc + 8 * quad];
  float4v acc[5];
  for (int mb = 0; mb < 5; ++mb) acc[mb] = *(const float4v*)&b80[16 * mb + 4 * quad];
  const float* xb = x + (size_t)b * N_C * N_PIX;
  for (int kc = 0; kc < 2; ++kc) {
    half8 bf;
    for (int j = 0; j < 8; ++j)
      bf[j] = (_Float16)xb[(size_t)(32 * kc + 8 * quad + j) * N_PIX + n];
    for (int mb = 0; mb < 5; ++mb)
      acc[mb] = __builtin_amdgcn_mfma_f32_16x16x32_f16(wf[mb][kc], bf, acc[mb], 0, 0, 0);
  }
  {
    _Float16* dstK = K16 + ((size_t)b * N_PIX + n) * 8;
    _Float16* dstQ = Q16 + ((size_t)b * N_PIX + n) * 8;
    for (int r = 0; r < 4; ++r) {
      const int m = 4 * quad + r;
      const _Float16 v = (_Float16)acc[0][r];
      if (m < 8) dstK[m] = v; else dstQ[m - 8] = v;
    }
  }
  for (int mb = 1; mb < 5; ++mb)
    for (int r = 0; r < 4; ++r) {
      const int c = 4 * quad + r + 16 * (mb - 1);
      VT16[((size_t)b * N_C + c) * N_PIX + n] = (_Float16)acc[mb][r];
    }
  float sq = 0.f;
  if (quad < 2)
    for (int r = 0; r < 4; ++r) sq += acc[0][r] * acc[0][r];
  sq += __shfl_xor(sq, 16, 64);
  for (int d = 1; d < 64; d <<= 1) sq = fmaxf(sq, __shfl_xor(sq, d, 64));
  if (lane == 0) atomicMax(&maxKu[b], __float_as_uint(sq));
}

// ---------------------------------------------------------------- k_attn
// 576 blocks x 4 waves, 32-query tile; round r (0..71): wave w owns keys
// [128r+32w, +32). No barriers in the loop. K/V staged to per-wave LDS via
// global_load_lds (double-buffered, 1-round lookahead, s_waitcnt vmcnt(5)).

__device__ __forceinline__ void gload16(const _Float16* g, _Float16* l) {
  __builtin_amdgcn_global_load_lds(
      (const __attribute__((address_space(1))) void*)g,
      (__attribute__((address_space(3))) void*)l, 16, 0, 0);
}

#define VMWAIT5() asm volatile("s_waitcnt vmcnt(5)" ::: "memory")
#define DS2(D0, D1, P0, P1)                                              \
  asm volatile("ds_read_b128 %0, %2\n\t"                                 \
               "ds_read_b128 %1, %3\n\t"                                 \
               "s_waitcnt lgkmcnt(0)"                                    \
               : "=&v"(D0), "=&v"(D1) : "v"(P0), "v"(P1) : "memory")
#define DS4(D0, D1, D2, D3, P0, P1, P2, P3)                              \
  asm volatile("ds_read_b128 %0, %4\n\t"                                 \
               "ds_read_b128 %1, %5\n\t"                                 \
               "ds_read_b128 %2, %6\n\t"                                 \
               "ds_read_b128 %3, %7\n\t"                                 \
               "s_waitcnt lgkmcnt(0)"                                    \
               : "=&v"(D0), "=&v"(D1), "=&v"(D2), "=&v"(D3)              \
               : "v"(P0), "v"(P1), "v"(P2), "v"(P3) : "memory")
typedef const __attribute__((address_space(3))) _Float16* lds_cp;

__global__ __launch_bounds__(256, 2) void k_attn(const _Float16* __restrict__ K16,
                                                 const _Float16* __restrict__ Q16,
                                                 const _Float16* __restrict__ VT16,
                                                 const unsigned* __restrict__ maxKu,
                                                 const float* __restrict__ x,
                                                 const float* __restrict__ gamma,
                                                 float* __restrict__ out) {
  __shared__ __align__(16) _Float16 Kld[2][4][64 * 8];   // [slot][wave][32 keys(+dup) x 8]
  __shared__ __align__(16) _Float16 Vld[2][4][64 * 32];  // [slot][wave][64 ch][32 keys]
  __shared__ __align__(16) _Float16 Pld[4][32 * 40];     // per-wave private P
  __shared__ float Lsh[4][32];
  __shared__ float Osh[4][64][17];                       // two-phase merge buffer
  const int wave = threadIdx.x >> 6;
  const int lane = threadIdx.x & 63;
  const int lane15 = lane & 15, quad = lane >> 4;
  const int tile = blockIdx.x;            // 0..575
  const int b = tile / 288;
  const int jb = (tile % 288) * 32;
  const float gm = gamma[0];
  const _Float16* Kb = K16 + (size_t)b * N_PIX * 8;
  const _Float16* Vb = VT16 + (size_t)b * N_C * N_PIX;
  _Float16* Pl = Pld[wave];

  // Q frags (B-operand): quad0 holds Q[query][k=0..7]; other quads zero.
  half8 qf0 = {}, qf1 = {};
  if (quad == 0) {
    qf0 = *(const half8*)(Q16 + ((size_t)b * N_PIX + jb + lane15) * 8);
    qf1 = *(const half8*)(Q16 + ((size_t)b * N_PIX + jb + 16 + lane15) * 8);
  }
  // bound-max per query (consumes qf pre-loop -> no VMEM waits inside loop)
  const float maxK = sqrtf(__uint_as_float(maxKu[b]));
  float nq0 = 0.f, nq1 = 0.f;
  if (quad == 0)
#pragma unroll
    for (int j = 0; j < 8; ++j) {
      nq0 += (float)qf0[j] * (float)qf0[j];
      nq1 += (float)qf1[j] * (float)qf1[j];
    }
  nq0 = __shfl(nq0, lane15, 64);
  nq1 = __shfl(nq1, lane15, 64);
  const float M0 = sqrtf(nq0) * maxK - EXP_SHIFT;
  const float M1 = sqrtf(nq1) * maxK - EXP_SHIFT;

  float4v a00 = {0.f,0.f,0.f,0.f}, a01 = {0.f,0.f,0.f,0.f}, a02 = {0.f,0.f,0.f,0.f}, a03 = {0.f,0.f,0.f,0.f};
  float4v a10 = {0.f,0.f,0.f,0.f}, a11 = {0.f,0.f,0.f,0.f}, a12 = {0.f,0.f,0.f,0.f}, a13 = {0.f,0.f,0.f,0.f};
  float ls0 = 0.f, ls1 = 0.f;
  const float4v f4z = {0.f, 0.f, 0.f, 0.f};

  // staging: 5 gload_lds per round (1 K + 4 V), all own-wave.
#define STAGE(SLOT, I0)                                                          \
  {                                                                              \
    const int _i = (I0);                                                         \
    gload16(Kb + (size_t)(_i + (lane & 31)) * 8, &Kld[SLOT][wave][0]);           \
    gload16(Vb + (size_t)(lane >> 2) * N_PIX + _i + (lane & 3) * 8,              \
            &Vld[SLOT][wave][0]);                                                \
    gload16(Vb + (size_t)(16 + (lane >> 2)) * N_PIX + _i + (lane & 3) * 8,       \
            &Vld[SLOT][wave][512]);                                              \
    gload16(Vb + (size_t)(32 + (lane >> 2)) * N_PIX + _i + (lane & 3) * 8,       \
            &Vld[SLOT][wave][1024]);                                             \
    gload16(Vb + (size_t)(48 + (lane >> 2)) * N_PIX + _i + (lane & 3) * 8,       \
            &Vld[SLOT][wave][1536]);                                             \
  }

  STAGE(0, 32 * wave)   // round 0

#pragma unroll 1
  for (int r = 0; r < 72; ++r) {
    const int slot = r & 1, nslot = slot ^ 1;
    const int i1 = (r < 71) ? (128 * (r + 1) + 32 * wave) : (128 * 71 + 32 * wave);
    STAGE(nslot, i1)                      // prefetch next round (or harmless reload)
    VMWAIT5();                            // this round's 5 staging loads done
    // K A-frags: all lanes read the per-lane15 key row (finite for all quads;
    // quads 1-3 multiply against qf==0).
    int4v k0i, k1i;
    {
      lds_cp pk0 = (lds_cp)&Kld[slot][wave][lane15 * 8];
      lds_cp pk1 = (lds_cp)&Kld[slot][wave][(16 + lane15) * 8];
      DS2(k0i, k1i, pk0, pk1);
    }
    const half8 kf0 = __builtin_bit_cast(half8, k0i);
    const half8 kf1 = __builtin_bit_cast(half8, k1i);
    float4v s00 = __builtin_amdgcn_mfma_f32_16x16x32_f16(kf0, qf0, f4z, 0, 0, 0);
    float4v s10 = __builtin_amdgcn_mfma_f32_16x16x32_f16(kf1, qf0, f4z, 0, 0, 0);
    float4v s01 = __builtin_amdgcn_mfma_f32_16x16x32_f16(kf0, qf1, f4z, 0, 0, 0);
    float4v s11 = __builtin_amdgcn_mfma_f32_16x16x32_f16(kf1, qf1, f4z, 0, 0, 0);
    // p = exp2(S - M); f16-rounded lsum; P transpose (same-wave private LDS)
    half4v h00, h10, h01, h11;
#pragma unroll
    for (int rr = 0; rr < 4; ++rr) {
      const float p00 = __builtin_amdgcn_exp2f(s00[rr] - M0);
      const float p10 = __builtin_amdgcn_exp2f(s10[rr] - M0);
      const float p01 = __builtin_amdgcn_exp2f(s01[rr] - M1);
      const float p11 = __builtin_amdgcn_exp2f(s11[rr] - M1);
      h00[rr] = (_Float16)p00; ls0 += (float)h00[rr];
      h10[rr] = (_Float16)p10; ls0 += (float)h10[rr];
      h01[rr] = (_Float16)p01; ls1 += (float)h01[rr];
      h11[rr] = (_Float16)p11; ls1 += (float)h11[rr];
    }
    *(half4v*)&Pl[lane15 * 40 + 4 * quad] = h00;
    *(half4v*)&Pl[lane15 * 40 + 16 + 4 * quad] = h10;
    *(half4v*)&Pl[(16 + lane15) * 40 + 4 * quad] = h01;
    *(half4v*)&Pl[(16 + lane15) * 40 + 16 + 4 * quad] = h11;
    const half8 pf0 = *(const half8*)&Pl[lane15 * 40 + 8 * quad];
    const half8 pf1 = *(const half8*)&Pl[(16 + lane15) * 40 + 8 * quad];
    // V B-frags from this wave's slot: channel 16*cb + lane15, keys 8*quad..
    int4v v0i, v1i, v2i, v3i;
    {
      lds_cp pv0 = (lds_cp)&Vld[slot][wave][lane15 * 32 + 8 * quad];
      lds_cp pv1 = (lds_cp)&Vld[slot][wave][512 + lane15 * 32 + 8 * quad];
      lds_cp pv2 = (lds_cp)&Vld[slot][wave][1024 + lane15 * 32 + 8 * quad];
      lds_cp pv3 = (lds_cp)&Vld[slot][wave][1536 + lane15 * 32 + 8 * quad];
      DS4(v0i, v1i, v2i, v3i, pv0, pv1, pv2, pv3);
    }
    a00 = __builtin_amdgcn_mfma_f32_16x16x32_f16(pf0, __builtin_bit_cast(half8, v0i), a00, 0, 0, 0);
    a01 = __builtin_amdgcn_mfma_f32_16x16x32_f16(pf0, __builtin_bit_cast(half8, v1i), a01, 0, 0, 0);
    a02 = __builtin_amdgcn_mfma_f32_16x16x32_f16(pf0, __builtin_bit_cast(half8, v2i), a02, 0, 0, 0);
    a03 = __builtin_amdgcn_mfma_f32_16x16x32_f16(pf0, __builtin_bit_cast(half8, v3i), a03, 0, 0, 0);
    a10 = __builtin_amdgcn_mfma_f32_16x16x32_f16(pf1, __builtin_bit_cast(half8, v0i), a10, 0, 0, 0);
    a11 = __builtin_amdgcn_mfma_f32_16x16x32_f16(pf1, __builtin_bit_cast(half8, v1i), a11, 0, 0, 0);
    a12 = __builtin_amdgcn_mfma_f32_16x16x32_f16(pf1, __builtin_bit_cast(half8, v2i), a12, 0, 0, 0);
    a13 = __builtin_amdgcn_mfma_f32_16x16x32_f16(pf1, __builtin_bit_cast(half8, v3i), a13, 0, 0, 0);
  }
#undef STAGE
  asm volatile("s_waitcnt vmcnt(0)" ::: "memory");  // drain dangling staging

  // ---- merge across waves (key-split partials), two phases over Osh.
  ls0 += __shfl_xor(ls0, 16, 64); ls0 += __shfl_xor(ls0, 32, 64);
  ls1 += __shfl_xor(ls1, 16, 64); ls1 += __shfl_xor(ls1, 32, 64);
  if (quad == 0) { Lsh[wave][lane15] = ls0; Lsh[wave][16 + lane15] = ls1; }
#pragma unroll
  for (int rr = 0; rr < 4; ++rr) {
    Osh[wave][lane][rr]      = a00[rr];
    Osh[wave][lane][4 + rr]  = a01[rr];
    Osh[wave][lane][8 + rr]  = a02[rr];
    Osh[wave][lane][12 + rr] = a03[rr];
  }
  __syncthreads();
  float4v lt0 = {0.f, 0.f, 0.f, 0.f}, lt1 = {0.f, 0.f, 0.f, 0.f};
#pragma unroll
  for (int w = 0; w < 4; ++w) {
    const float4v a = *(const float4v*)&Lsh[w][4 * quad];
    const float4v c = *(const float4v*)&Lsh[w][16 + 4 * quad];
#pragma unroll
    for (int rr = 0; rr < 4; ++rr) { lt0[rr] += a[rr]; lt1[rr] += c[rr]; }
  }
  const int ch = 16 * wave + lane15;
  const float* xb = x + (size_t)b * N_C * N_PIX;
  float* ob = out + (size_t)b * N_C * N_PIX;
  {
    float4v osum = {0.f, 0.f, 0.f, 0.f};
#pragma unroll
    for (int w = 0; w < 4; ++w)
#pragma unroll
      for (int rr = 0; rr < 4; ++rr) osum[rr] += Osh[w][lane][4 * wave + rr];
    const size_t idx = (size_t)ch * N_PIX + jb + 4 * quad;
    const float4v xr = *(const float4v*)(xb + idx);
    float4v o;
#pragma unroll
    for (int rr = 0; rr < 4; ++rr) o[rr] = gm * osum[rr] / lt0[rr] + xr[rr];
    *(float4v*)(ob + idx) = o;
  }
  __syncthreads();   // everyone done reading phase-1 Osh
#pragma unroll
  for (int rr = 0; rr < 4; ++rr) {
    Osh[wave][lane][rr]      = a10[rr];
    Osh[wave][lane][4 + rr]  = a11[rr];
    Osh[wave][lane][8 + rr]  = a12[rr];
    Osh[wave][lane][12 + rr] = a13[rr];
  }
  __syncthreads();
  {
    float4v osum = {0.f, 0.f, 0.f, 0.f};
#pragma unroll
    for (int w = 0; w < 4; ++w)
#pragma unroll
      for (int rr = 0; rr < 4; ++rr) osum[rr] += Osh[w][lane][4 * wave + rr];
    const size_t idx = (size_t)ch * N_PIX + jb + 16 + 4 * quad;
    const float4v xr = *(const float4v*)(xb + idx);
    float4v o;
#pragma unroll
    for (int rr = 0; rr < 4; ++rr) o[rr] = gm * osum[rr] / lt1[rr] + xr[rr];
    *(float4v*)(ob + idx) = o;
  }
}

// ---------------------------------------------------------------- launch
extern "C" void kernel_launch(void* const* d_in, const int* in_sizes, int n_in,
                              void* d_out, int out_size, void* d_ws, size_t ws_size,
                              hipStream_t stream) {
  const float* x     = (const float*)d_in[0];
  const float* Wq    = (const float*)d_in[1];
  const float* bq    = (const float*)d_in[2];
  const float* Wk    = (const float*)d_in[3];
  const float* bk    = (const float*)d_in[4];
  const float* Wv    = (const float*)d_in[5];
  const float* bv    = (const float*)d_in[6];
  const float* gamma = (const float*)d_in[7];
  float* out = (float*)d_out;

  char* ws = (char*)d_ws;
  float*    sig   = (float*)ws;                       // 4 floats
  unsigned* maxKu = (unsigned*)(ws + 16);             // 2 uints (float bits, >=0)
  float*    b80   = (float*)(ws + 32);                // 80 floats
  _Float16* W16   = (_Float16*)(ws + 512);            // 80*64 halves
  _Float16* K16   = (_Float16*)(ws + 10752);          // 2*9216*8
  _Float16* Q16   = (_Float16*)(ws + 10752 + 294912); // 2*9216*8
  _Float16* VT16  = (_Float16*)(ws + 10752 + 2 * 294912); // 2*64*9216

  hipLaunchKernelGGL(k_sigma, dim3(3), dim3(64), 0, stream, Wq, Wk, Wv, sig);
  hipLaunchKernelGGL(k_wconv, dim3(1), dim3(128), 0, stream, Wq, bq, Wk, bk, Wv, bv, sig, W16, b80, maxKu);
  hipLaunchKernelGGL(k_fgh, dim3(288), dim3(256), 0, stream, x, W16, b80, K16, Q16, VT16, maxKu);
  hipLaunchKernelGGL(k_attn, dim3(576), dim3(256), 0, stream, K16, Q16, VT16, maxKu, x, gamma, out);
}

// Round 10
// 178.097 us; speedup vs baseline: 1.2407x; 1.1119x over previous
//
#include <hip/hip_runtime.h>

// SelfAttention (SAGAN-style) on MI355X.
// B=2, C=64, C8=8, H=W=96, N=9216.  out = gamma * Attn(g,f,h) + x
//   K = f = (Wq/sq) x + bq   (pre-scaled by log2e; softmax in exp2 domain)
//   Q = g = (Wk/sk) x + bk
//   V = h = (Wv/sv) x + bv
// softmax over keys i; head_dim 8 (zero-padded to MFMA K=32), dv=64.
//
// R10: DS-pipe attack. R6==R9==101us despite opposite barrier structure =>
// bottleneck is the shared LDS pipe (~250 cyc/wave-round, 67us floor), with
// V ds_read_b128 4-way bank-conflicted (channel stride 64B; 6.6M conflicts).
// Fixes: (1) XOR-swizzled V staging - global address per lane permuted so
// slot = g ^ ((c>>1)&3); consecutive-8-lane read phases then cover all 8
// bank groups -> conflict-free. (2) LDS union: per-wave 12.8KB region
// (V 2x4KB | K 2x1KB | P 2.5KB), epilogue Osh/Lsh aliased into own region
// -> 51200B total -> 3 blocks/CU. (3) k_wconv folded into k_fgh; 3 launches.
// Numerics unchanged (M = |Q|*max|K'| - 12, f16 P, f16-rounded lsum).

#define N_PIX 9216
#define N_B   2
#define N_C   64

typedef _Float16 half8  __attribute__((ext_vector_type(8)));
typedef _Float16 half4v __attribute__((ext_vector_type(4)));
typedef float    float4v __attribute__((ext_vector_type(4)));
typedef int      int4v  __attribute__((ext_vector_type(4)));

#define LOG2E 1.44269504088896340736f
#define EXP_SHIFT 12.0f

// ---------------------------------------------------------------- k_sigma
__global__ __launch_bounds__(64) void k_sigma(const float* __restrict__ Wq,
                                              const float* __restrict__ Wk,
                                              const float* __restrict__ Wv,
                                              float* __restrict__ sig,
                                              unsigned* __restrict__ maxKu) {
  __shared__ float G8[8][8];
  __shared__ float Wl[64 * 64];
  __shared__ _Float16 Wh[64 * 80];
  __shared__ _Float16 Gh[64 * 80];
  const int t = threadIdx.x;
  const int mat = blockIdx.x;
  if (mat == 0 && t < 2) maxKu[t] = 0u;   // init for k_fgh's atomicMax
  if (mat < 2) {
    const float* W = (mat == 0) ? Wq : Wk;
    const int i = t >> 3, j = t & 7;
    float g = 0.f;
    for (int c = 0; c < 64; ++c) g += W[i * 64 + c] * W[j * 64 + c];
    G8[i][j] = g;
    __syncthreads();
    const int L = t & 7;
    float G0[8], Gr[8];
    for (int k = 0; k < 8; ++k) { G0[k] = G8[L][k]; Gr[k] = G0[k]; }
    for (int it = 0; it < 8; ++it) {
      float g2[8] = {0, 0, 0, 0, 0, 0, 0, 0};
      for (int k = 0; k < 8; ++k) {
        float gik = Gr[k];
        for (int jj = 0; jj < 8; ++jj) g2[jj] += gik * __shfl(Gr[jj], k, 64);
      }
      float mx = 0.f;
      for (int jj = 0; jj < 8; ++jj) mx = fmaxf(mx, fabsf(g2[jj]));
      for (int d = 1; d < 8; d <<= 1) mx = fmaxf(mx, __shfl_xor(mx, d, 64));
      float r = 1.f / mx;
      for (int jj = 0; jj < 8; ++jj) Gr[jj] = g2[jj] * r;
    }
    float u = 0.f;
    for (int jj = 0; jj < 8; ++jj) u += Gr[jj];
    float y = 0.f;
    for (int k = 0; k < 8; ++k) y += G0[k] * __shfl(u, k, 64);
    float nu = u * y, de = u * u;
    for (int d = 1; d < 8; d <<= 1) { nu += __shfl_xor(nu, d, 64); de += __shfl_xor(de, d, 64); }
    if (t == 0) sig[mat] = sqrtf(nu / de);
  } else {
    for (int idx = t; idx < 4096; idx += 64) Wl[idx] = Wv[idx];
    __syncthreads();
    for (int idx = t; idx < 4096; idx += 64) Wh[(idx >> 6) * 80 + (idx & 63)] = (_Float16)Wl[idx];
    __syncthreads();
    const int lane15 = t & 15, quad = t >> 4;
    half8 fr[4][2];
    for (int rb = 0; rb < 4; ++rb)
      for (int kc = 0; kc < 2; ++kc)
        fr[rb][kc] = *(const half8*)&Wh[(lane15 + 16 * rb) * 80 + 32 * kc + 8 * quad];
    float4v D[4][4];
    for (int mb = 0; mb < 4; ++mb) for (int nb = 0; nb < 4; ++nb) D[mb][nb] = (float4v){0.f, 0.f, 0.f, 0.f};
    for (int kc = 0; kc < 2; ++kc)
      for (int mb = 0; mb < 4; ++mb)
        for (int nb = 0; nb < 4; ++nb)
          D[mb][nb] = __builtin_amdgcn_mfma_f32_16x16x32_f16(fr[mb][kc], fr[nb][kc], D[mb][nb], 0, 0, 0);
    for (int it = 0; it < 8; ++it) {
      float mx = 0.f;
      for (int mb = 0; mb < 4; ++mb) for (int nb = 0; nb < 4; ++nb) for (int r = 0; r < 4; ++r)
        mx = fmaxf(mx, fabsf(D[mb][nb][r]));
      for (int d = 1; d < 64; d <<= 1) mx = fmaxf(mx, __shfl_xor(mx, d, 64));
      float rs = 1.f / mx;
      for (int mb = 0; mb < 4; ++mb) for (int nb = 0; nb < 4; ++nb) for (int r = 0; r < 4; ++r)
        Gh[(4 * quad + r + 16 * mb) * 80 + lane15 + 16 * nb] = (_Float16)(D[mb][nb][r] * rs);
      __syncthreads();
      if (it == 7) break;
      for (int rb = 0; rb < 4; ++rb)
        for (int kc = 0; kc < 2; ++kc)
          fr[rb][kc] = *(const half8*)&Gh[(lane15 + 16 * rb) * 80 + 32 * kc + 8 * quad];
      for (int mb = 0; mb < 4; ++mb) for (int nb = 0; nb < 4; ++nb) D[mb][nb] = (float4v){0.f, 0.f, 0.f, 0.f};
      for (int kc = 0; kc < 2; ++kc)
        for (int mb = 0; mb < 4; ++mb)
          for (int nb = 0; nb < 4; ++nb)
            D[mb][nb] = __builtin_amdgcn_mfma_f32_16x16x32_f16(fr[mb][kc], fr[nb][kc], D[mb][nb], 0, 0, 0);
      __syncthreads();
    }
    float u = 0.f;
    for (int c = 0; c < 64; ++c) u += (float)Gh[t * 80 + c];
    float z = 0.f;
    for (int i2 = 0; i2 < 64; ++i2) z += Wl[i2 * 64 + t] * __shfl(u, i2, 64);
    float nu = z * z, de = u * u;
    for (int d = 1; d < 64; d <<= 1) { nu += __shfl_xor(nu, d, 64); de += __shfl_xor(de, d, 64); }
    if (t == 0) sig[2] = sqrtf(nu / de);
  }
}

// ---------------------------------------------------------------- k_fgh
// Conv GEMM + folded weight normalization (into LDS) + max|K'|^2 atomicMax.
__global__ __launch_bounds__(256) void k_fgh(const float* __restrict__ x,
                                             const float* __restrict__ Wq, const float* __restrict__ bq,
                                             const float* __restrict__ Wk, const float* __restrict__ bk,
                                             const float* __restrict__ Wv, const float* __restrict__ bv,
                                             const float* __restrict__ sig,
                                             _Float16* __restrict__ K16,
                                             _Float16* __restrict__ Q16,
                                             _Float16* __restrict__ VT16,
                                             unsigned* __restrict__ maxKu) {
  __shared__ _Float16 Wsh[80 * 64];
  __shared__ float bsh[80];
  const int t = threadIdx.x;
  const float iq = LOG2E / sig[0], ik = 1.0f / sig[1], iv = 1.0f / sig[2];
  for (int idx = t; idx < 80 * 64; idx += 256) {
    const int m = idx >> 6, c = idx & 63;
    float v;
    if (m < 8)       v = Wq[m * 64 + c] * iq;
    else if (m < 16) v = Wk[(m - 8) * 64 + c] * ik;
    else             v = Wv[(m - 16) * 64 + c] * iv;
    Wsh[idx] = (_Float16)v;
  }
  if (t < 80) {
    float v;
    if (t < 8)       v = bq[t] * LOG2E;
    else if (t < 16) v = bk[t - 8];
    else             v = bv[t - 16];
    bsh[t] = v;
  }
  __syncthreads();
  const int wave = t >> 6;
  const int lane = t & 63;
  const int lane15 = lane & 15, quad = lane >> 4;
  const int tile = blockIdx.x * 4 + wave;
  const int b = tile / 576;
  const int n = (tile % 576) * 16 + lane15;
  half8 wf[5][2];
  for (int mb = 0; mb < 5; ++mb)
    for (int kc = 0; kc < 2; ++kc)
      wf[mb][kc] = *(const half8*)&Wsh[(lane15 + 16 * mb) * 64 + 32 * kc + 8 * quad];
  float4v acc[5];
  for (int mb = 0; mb < 5; ++mb) acc[mb] = *(const float4v*)&bsh[16 * mb + 4 * quad];
  const float* xb = x + (size_t)b * N_C * N_PIX;
  for (int kc = 0; kc < 2; ++kc) {
    half8 bf;
    for (int j = 0; j < 8; ++j)
      bf[j] = (_Float16)xb[(size_t)(32 * kc + 8 * quad + j) * N_PIX + n];
    for (int mb = 0; mb < 5; ++mb)
      acc[mb] = __builtin_amdgcn_mfma_f32_16x16x32_f16(wf[mb][kc], bf, acc[mb], 0, 0, 0);
  }
  {
    _Float16* dstK = K16 + ((size_t)b * N_PIX + n) * 8;
    _Float16* dstQ = Q16 + ((size_t)b * N_PIX + n) * 8;
    for (int r = 0; r < 4; ++r) {
      const int m = 4 * quad + r;
      const _Float16 v = (_Float16)acc[0][r];
      if (m < 8) dstK[m] = v; else dstQ[m - 8] = v;
    }
  }
  for (int mb = 1; mb < 5; ++mb)
    for (int r = 0; r < 4; ++r) {
      const int c = 4 * quad + r + 16 * (mb - 1);
      VT16[((size_t)b * N_C + c) * N_PIX + n] = (_Float16)acc[mb][r];
    }
  float sq = 0.f;
  if (quad < 2)
    for (int r = 0; r < 4; ++r) sq += acc[0][r] * acc[0][r];
  sq += __shfl_xor(sq, 16, 64);
  for (int d = 1; d < 64; d <<= 1) sq = fmaxf(sq, __shfl_xor(sq, d, 64));
  if (lane == 0) atomicMax(&maxKu[b], __float_as_uint(sq));
}

// ---------------------------------------------------------------- k_attn
// 576 blocks x 4 waves, 32-query tile; round r (0..71): wave w owns keys
// [128r+32w, +32). No barriers in the loop. K/V staged to the wave's LDS
// region via global_load_lds (double-buffered, 1-round lookahead, vmcnt(5)).
// V XOR-swizzled: granule g of channel c stored at slot g^((c>>1)&3) ->
// conflict-free b128 reads. Per-wave LDS region (6400 halves = 12.8 KB):
//   [0..2047]    V slot 0   (64 ch x 32 keys, swizzled)
//   [2048..4095] V slot 1
//   [4096..4607] K slot 0   (64 rows x 8)
//   [4608..5119] K slot 1
//   [5120..6399] P          (32 q x 40)
// Epilogue Osh(lane-major, stride 17 f32) + Lsh aliased at region start.

__device__ __forceinline__ void gload16(const _Float16* g, _Float16* l) {
  __builtin_amdgcn_global_load_lds(
      (const __attribute__((address_space(1))) void*)g,
      (__attribute__((address_space(3))) void*)l, 16, 0, 0);
}

#define VMWAIT5() asm volatile("s_waitcnt vmcnt(5)" ::: "memory")
#define DS2(D0, D1, P0, P1)                                              \
  asm volatile("ds_read_b128 %0, %2\n\t"                                 \
               "ds_read_b128 %1, %3\n\t"                                 \
               "s_waitcnt lgkmcnt(0)"                                    \
               : "=&v"(D0), "=&v"(D1) : "v"(P0), "v"(P1) : "memory")
#define DS4(D0, D1, D2, D3, P0, P1, P2, P3)                              \
  asm volatile("ds_read_b128 %0, %4\n\t"                                 \
               "ds_read_b128 %1, %5\n\t"                                 \
               "ds_read_b128 %2, %6\n\t"                                 \
               "ds_read_b128 %3, %7\n\t"                                 \
               "s_waitcnt lgkmcnt(0)"                                    \
               : "=&v"(D0), "=&v"(D1), "=&v"(D2), "=&v"(D3)              \
               : "v"(P0), "v"(P1), "v"(P2), "v"(P3) : "memory")
typedef const __attribute__((address_space(3))) _Float16* lds_cp;

__global__ __launch_bounds__(256, 3) void k_attn(const _Float16* __restrict__ K16,
                                                 const _Float16* __restrict__ Q16,
                                                 const _Float16* __restrict__ VT16,
                                                 const unsigned* __restrict__ maxKu,
                                                 const float* __restrict__ x,
                                                 const float* __restrict__ gamma,
                                                 float* __restrict__ out) {
  __shared__ __align__(16) _Float16 SM[4][6400];   // 51200 B total -> 3 blocks/CU
  const int wave = threadIdx.x >> 6;
  const int lane = threadIdx.x & 63;
  const int lane15 = lane & 15, quad = lane >> 4;
  const int tile = blockIdx.x;            // 0..575
  const int b = tile / 288;
  const int jb = (tile % 288) * 32;
  const float gm = gamma[0];
  const _Float16* Kb = K16 + (size_t)b * N_PIX * 8;
  const _Float16* Vb = VT16 + (size_t)b * N_C * N_PIX;
  _Float16* Rg = SM[wave];                // this wave's region
  _Float16* Pl = Rg + 5120;
  // staging lane mapping (constant): channel-local cl, LDS slot kk, swizzled
  // source granule gsw = kk ^ ((cl>>1)&3).
  const int cl = lane >> 2, kk = lane & 3;
  const int gsw = (kk ^ ((cl >> 1) & 3)) * 8;
  const int ksrc = lane & 31;
  // V read slot (per lane): granule quad lives at slot quad^((lane15>>1)&3)
  const int vslot = (quad ^ ((lane15 >> 1) & 3)) * 8;

  // Q frags (B-operand): quad0 holds Q[query][k=0..7]; other quads zero.
  half8 qf0 = {}, qf1 = {};
  if (quad == 0) {
    qf0 = *(const half8*)(Q16 + ((size_t)b * N_PIX + jb + lane15) * 8);
    qf1 = *(const half8*)(Q16 + ((size_t)b * N_PIX + jb + 16 + lane15) * 8);
  }
  // bound-max per query (consumes qf pre-loop -> no VMEM waits inside loop)
  const float maxK = sqrtf(__uint_as_float(maxKu[b]));
  float nq0 = 0.f, nq1 = 0.f;
  if (quad == 0)
#pragma unroll
    for (int j = 0; j < 8; ++j) {
      nq0 += (float)qf0[j] * (float)qf0[j];
      nq1 += (float)qf1[j] * (float)qf1[j];
    }
  nq0 = __shfl(nq0, lane15, 64);
  nq1 = __shfl(nq1, lane15, 64);
  const float M0 = sqrtf(nq0) * maxK - EXP_SHIFT;
  const float M1 = sqrtf(nq1) * maxK - EXP_SHIFT;

  float4v a00 = {0.f,0.f,0.f,0.f}, a01 = {0.f,0.f,0.f,0.f}, a02 = {0.f,0.f,0.f,0.f}, a03 = {0.f,0.f,0.f,0.f};
  float4v a10 = {0.f,0.f,0.f,0.f}, a11 = {0.f,0.f,0.f,0.f}, a12 = {0.f,0.f,0.f,0.f}, a13 = {0.f,0.f,0.f,0.f};
  float ls0 = 0.f, ls1 = 0.f;
  const float4v f4z = {0.f, 0.f, 0.f, 0.f};

  // staging: 5 gload_lds per round (1 K + 4 V), all own-wave, swizzled V.
#define STAGE(SLOT, I0)                                                          \
  {                                                                              \
    const int _i = (I0);                                                         \
    gload16(Kb + (size_t)(_i + ksrc) * 8, Rg + 4096 + (SLOT) * 512);             \
    gload16(Vb + (size_t)cl * N_PIX + _i + gsw,        Rg + (SLOT) * 2048);      \
    gload16(Vb + (size_t)(16 + cl) * N_PIX + _i + gsw, Rg + (SLOT) * 2048 + 512);\
    gload16(Vb + (size_t)(32 + cl) * N_PIX + _i + gsw, Rg + (SLOT) * 2048 + 1024);\
    gload16(Vb + (size_t)(48 + cl) * N_PIX + _i + gsw, Rg + (SLOT) * 2048 + 1536);\
  }

  STAGE(0, 32 * wave)   // round 0

#pragma unroll 1
  for (int r = 0; r < 72; ++r) {
    const int slot = r & 1, nslot = slot ^ 1;
    const int i1 = (r < 71) ? (128 * (r + 1) + 32 * wave) : (128 * 71 + 32 * wave);
    STAGE(nslot, i1)                      // prefetch next round (or harmless reload)
    VMWAIT5();                            // this round's 5 staging loads done
    int4v k0i, k1i;
    {
      lds_cp pk0 = (lds_cp)(Rg + 4096 + slot * 512 + lane15 * 8);
      lds_cp pk1 = (lds_cp)(Rg + 4096 + slot * 512 + 128 + lane15 * 8);
      DS2(k0i, k1i, pk0, pk1);
    }
    const half8 kf0 = __builtin_bit_cast(half8, k0i);
    const half8 kf1 = __builtin_bit_cast(half8, k1i);
    float4v s00 = __builtin_amdgcn_mfma_f32_16x16x32_f16(kf0, qf0, f4z, 0, 0, 0);
    float4v s10 = __builtin_amdgcn_mfma_f32_16x16x32_f16(kf1, qf0, f4z, 0, 0, 0);
    float4v s01 = __builtin_amdgcn_mfma_f32_16x16x32_f16(kf0, qf1, f4z, 0, 0, 0);
    float4v s11 = __builtin_amdgcn_mfma_f32_16x16x32_f16(kf1, qf1, f4z, 0, 0, 0);
    half4v h00, h10, h01, h11;
#pragma unroll
    for (int rr = 0; rr < 4; ++rr) {
      const float p00 = __builtin_amdgcn_exp2f(s00[rr] - M0);
      const float p10 = __builtin_amdgcn_exp2f(s10[rr] - M0);
      const float p01 = __builtin_amdgcn_exp2f(s01[rr] - M1);
      const float p11 = __builtin_amdgcn_exp2f(s11[rr] - M1);
      h00[rr] = (_Float16)p00; ls0 += (float)h00[rr];
      h10[rr] = (_Float16)p10; ls0 += (float)h10[rr];
      h01[rr] = (_Float16)p01; ls1 += (float)h01[rr];
      h11[rr] = (_Float16)p11; ls1 += (float)h11[rr];
    }
    *(half4v*)&Pl[lane15 * 40 + 4 * quad] = h00;
    *(half4v*)&Pl[lane15 * 40 + 16 + 4 * quad] = h10;
    *(half4v*)&Pl[(16 + lane15) * 40 + 4 * quad] = h01;
    *(half4v*)&Pl[(16 + lane15) * 40 + 16 + 4 * quad] = h11;
    const half8 pf0 = *(const half8*)&Pl[lane15 * 40 + 8 * quad];
    const half8 pf1 = *(const half8*)&Pl[(16 + lane15) * 40 + 8 * quad];
    // V B-frags (swizzle-corrected slot)
    int4v v0i, v1i, v2i, v3i;
    {
      lds_cp pv0 = (lds_cp)(Rg + slot * 2048 + lane15 * 32 + vslot);
      lds_cp pv1 = (lds_cp)(Rg + slot * 2048 + 512 + lane15 * 32 + vslot);
      lds_cp pv2 = (lds_cp)(Rg + slot * 2048 + 1024 + lane15 * 32 + vslot);
      lds_cp pv3 = (lds_cp)(Rg + slot * 2048 + 1536 + lane15 * 32 + vslot);
      DS4(v0i, v1i, v2i, v3i, pv0, pv1, pv2, pv3);
    }
    a00 = __builtin_amdgcn_mfma_f32_16x16x32_f16(pf0, __builtin_bit_cast(half8, v0i), a00, 0, 0, 0);
    a01 = __builtin_amdgcn_mfma_f32_16x16x32_f16(pf0, __builtin_bit_cast(half8, v1i), a01, 0, 0, 0);
    a02 = __builtin_amdgcn_mfma_f32_16x16x32_f16(pf0, __builtin_bit_cast(half8, v2i), a02, 0, 0, 0);
    a03 = __builtin_amdgcn_mfma_f32_16x16x32_f16(pf0, __builtin_bit_cast(half8, v3i), a03, 0, 0, 0);
    a10 = __builtin_amdgcn_mfma_f32_16x16x32_f16(pf1, __builtin_bit_cast(half8, v0i), a10, 0, 0, 0);
    a11 = __builtin_amdgcn_mfma_f32_16x16x32_f16(pf1, __builtin_bit_cast(half8, v1i), a11, 0, 0, 0);
    a12 = __builtin_amdgcn_mfma_f32_16x16x32_f16(pf1, __builtin_bit_cast(half8, v2i), a12, 0, 0, 0);
    a13 = __builtin_amdgcn_mfma_f32_16x16x32_f16(pf1, __builtin_bit_cast(half8, v3i), a13, 0, 0, 0);
  }
#undef STAGE
  asm volatile("s_waitcnt vmcnt(0)" ::: "memory");  // drain dangling staging

  // ---- epilogue: alias Osh/Lsh into THIS WAVE's region (own data; no
  // barrier needed before writing). Osh: lane-major stride 17 f32; Lsh at
  // f32 offset 1088.
  float* Ow = (float*)Rg;
  float* Lw = (float*)Rg + 1088;
  ls0 += __shfl_xor(ls0, 16, 64); ls0 += __shfl_xor(ls0, 32, 64);
  ls1 += __shfl_xor(ls1, 16, 64); ls1 += __shfl_xor(ls1, 32, 64);
  if (quad == 0) { Lw[lane15] = ls0; Lw[16 + lane15] = ls1; }
#pragma unroll
  for (int rr = 0; rr < 4; ++rr) {
    Ow[lane * 17 + rr]      = a00[rr];
    Ow[lane * 17 + 4 + rr]  = a01[rr];
    Ow[lane * 17 + 8 + rr]  = a02[rr];
    Ow[lane * 17 + 12 + rr] = a03[rr];
  }
  __syncthreads();
  float4v lt0 = {0.f, 0.f, 0.f, 0.f}, lt1 = {0.f, 0.f, 0.f, 0.f};
#pragma unroll
  for (int w = 0; w < 4; ++w) {
    const float* Lww = (const float*)SM[w] + 1088;
#pragma unroll
    for (int rr = 0; rr < 4; ++rr) {
      lt0[rr] += Lww[4 * quad + rr];
      lt1[rr] += Lww[16 + 4 * quad + rr];
    }
  }
  const int ch = 16 * wave + lane15;
  const float* xb = x + (size_t)b * N_C * N_PIX;
  float* ob = out + (size_t)b * N_C * N_PIX;
  {
    float4v osum = {0.f, 0.f, 0.f, 0.f};
#pragma unroll
    for (int w = 0; w < 4; ++w) {
      const float* Oww = (const float*)SM[w];
#pragma unroll
      for (int rr = 0; rr < 4; ++rr) osum[rr] += Oww[lane * 17 + 4 * wave + rr];
    }
    const size_t idx = (size_t)ch * N_PIX + jb + 4 * quad;
    const float4v xr = *(const float4v*)(xb + idx);
    float4v o;
#pragma unroll
    for (int rr = 0; rr < 4; ++rr) o[rr] = gm * osum[rr] / lt0[rr] + xr[rr];
    *(float4v*)(ob + idx) = o;
  }
  __syncthreads();   // everyone done reading phase-1
#pragma unroll
  for (int rr = 0; rr < 4; ++rr) {
    Ow[lane * 17 + rr]      = a10[rr];
    Ow[lane * 17 + 4 + rr]  = a11[rr];
    Ow[lane * 17 + 8 + rr]  = a12[rr];
    Ow[lane * 17 + 12 + rr] = a13[rr];
  }
  __syncthreads();
  {
    float4v osum = {0.f, 0.f, 0.f, 0.f};
#pragma unroll
    for (int w = 0; w < 4; ++w) {
      const float* Oww = (const float*)SM[w];
#pragma unroll
      for (int rr = 0; rr < 4; ++rr) osum[rr] += Oww[lane * 17 + 4 * wave + rr];
    }
    const size_t idx = (size_t)ch * N_PIX + jb + 16 + 4 * quad;
    const float4v xr = *(const float4v*)(xb + idx);
    float4v o;
#pragma unroll
    for (int rr = 0; rr < 4; ++rr) o[rr] = gm * osum[rr] / lt1[rr] + xr[rr];
    *(float4v*)(ob + idx) = o;
  }
}

// ---------------------------------------------------------------- launch
extern "C" void kernel_launch(void* const* d_in, const int* in_sizes, int n_in,
                              void* d_out, int out_size, void* d_ws, size_t ws_size,
                              hipStream_t stream) {
  const float* x     = (const float*)d_in[0];
  const float* Wq    = (const float*)d_in[1];
  const float* bq    = (const float*)d_in[2];
  const float* Wk    = (const float*)d_in[3];
  const float* bk    = (const float*)d_in[4];
  const float* Wv    = (const float*)d_in[5];
  const float* bv    = (const float*)d_in[6];
  const float* gamma = (const float*)d_in[7];
  float* out = (float*)d_out;

  char* ws = (char*)d_ws;
  float*    sig   = (float*)ws;                       // 4 floats
  unsigned* maxKu = (unsigned*)(ws + 16);             // 2 uints (float bits, >=0)
  _Float16* K16   = (_Float16*)(ws + 10752);          // 2*9216*8
  _Float16* Q16   = (_Float16*)(ws + 10752 + 294912); // 2*9216*8
  _Float16* VT16  = (_Float16*)(ws + 10752 + 2 * 294912); // 2*64*9216

  hipLaunchKernelGGL(k_sigma, dim3(3), dim3(64), 0, stream, Wq, Wk, Wv, sig, maxKu);
  hipLaunchKernelGGL(k_fgh, dim3(288), dim3(256), 0, stream,
                     x, Wq, bq, Wk, bk, Wv, bv, sig, K16, Q16, VT16, maxKu);
  hipLaunchKernelGGL(k_attn, dim3(576), dim3(256), 0, stream, K16, Q16, VT16, maxKu, x, gamma, out);
}

// Round 11
// 174.976 us; speedup vs baseline: 1.2628x; 1.0178x over previous
//
#include <hip/hip_runtime.h>

// SelfAttention (SAGAN-style) on MI355X.
// B=2, C=64, C8=8, H=W=96, N=9216.  out = gamma * Attn(g,f,h) + x
//   K = f = (Wq/sq) x + bq   (pre-scaled by log2e; softmax in exp2 domain)
//   Q = g = (Wk/sk) x + bk
//   V = h = (Wv/sv) x + bv
// softmax over keys i; head_dim 8 (zero-padded), dv=64.
//
// R11: 32x32x16-MFMA restructure of k_attn. R10 accounting: DS pipe ~58%
// busy (190 cyc/wave-round), top consumers P-LDS round-trip (48) and K
// double-read (24). Now:
//  - S = one mfma_32x32x16 (A=K rows, B=Q cols), C preloaded with -M
//    (subtract free; M per-lane scalar since col=query=lane&31).
//  - P C-layout -> B-layout IN REGISTER: cvt_pkrtz pairs, then lane<->lane^32
//    exchange (4 shfl_xor + 12 cndmask). No P LDS at all.
//  - PV = 4x mfma_32x32x16 (A=V channel rows, B=P); V LDS-staged as before,
//    swizzle slot = g ^ (c&3) for the new read phases (<=2-way = free).
//  - LDS/wave 10.2KB (V 2x4K | K 2x1K); epilogue Osh/Lsh aliased in-region.
// Numerics unchanged (M = |Q|*max|K'| - 12, f16 P, f32 lsum of pre-round p).

#define N_PIX 9216
#define N_B   2
#define N_C   64

typedef _Float16 half8  __attribute__((ext_vector_type(8)));
typedef _Float16 half2v __attribute__((ext_vector_type(2)));
typedef float    float4v __attribute__((ext_vector_type(4)));
typedef float    float16v __attribute__((ext_vector_type(16)));
typedef int      int4v  __attribute__((ext_vector_type(4)));

#define LOG2E 1.44269504088896340736f
#define EXP_SHIFT 12.0f

// ---------------------------------------------------------------- k_sigma
__global__ __launch_bounds__(64) void k_sigma(const float* __restrict__ Wq,
                                              const float* __restrict__ Wk,
                                              const float* __restrict__ Wv,
                                              float* __restrict__ sig,
                                              unsigned* __restrict__ maxKu) {
  __shared__ float G8[8][8];
  __shared__ float Wl[64 * 64];
  __shared__ _Float16 Wh[64 * 80];
  __shared__ _Float16 Gh[64 * 80];
  const int t = threadIdx.x;
  const int mat = blockIdx.x;
  if (mat == 0 && t < 2) maxKu[t] = 0u;
  if (mat < 2) {
    const float* W = (mat == 0) ? Wq : Wk;
    const int i = t >> 3, j = t & 7;
    float g = 0.f;
    for (int c = 0; c < 64; ++c) g += W[i * 64 + c] * W[j * 64 + c];
    G8[i][j] = g;
    __syncthreads();
    const int L = t & 7;
    float G0[8], Gr[8];
    for (int k = 0; k < 8; ++k) { G0[k] = G8[L][k]; Gr[k] = G0[k]; }
    for (int it = 0; it < 8; ++it) {
      float g2[8] = {0, 0, 0, 0, 0, 0, 0, 0};
      for (int k = 0; k < 8; ++k) {
        float gik = Gr[k];
        for (int jj = 0; jj < 8; ++jj) g2[jj] += gik * __shfl(Gr[jj], k, 64);
      }
      float mx = 0.f;
      for (int jj = 0; jj < 8; ++jj) mx = fmaxf(mx, fabsf(g2[jj]));
      for (int d = 1; d < 8; d <<= 1) mx = fmaxf(mx, __shfl_xor(mx, d, 64));
      float r = 1.f / mx;
      for (int jj = 0; jj < 8; ++jj) Gr[jj] = g2[jj] * r;
    }
    float u = 0.f;
    for (int jj = 0; jj < 8; ++jj) u += Gr[jj];
    float y = 0.f;
    for (int k = 0; k < 8; ++k) y += G0[k] * __shfl(u, k, 64);
    float nu = u * y, de = u * u;
    for (int d = 1; d < 8; d <<= 1) { nu += __shfl_xor(nu, d, 64); de += __shfl_xor(de, d, 64); }
    if (t == 0) sig[mat] = sqrtf(nu / de);
  } else {
    for (int idx = t; idx < 4096; idx += 64) Wl[idx] = Wv[idx];
    __syncthreads();
    for (int idx = t; idx < 4096; idx += 64) Wh[(idx >> 6) * 80 + (idx & 63)] = (_Float16)Wl[idx];
    __syncthreads();
    const int lane15 = t & 15, quad = t >> 4;
    half8 fr[4][2];
    for (int rb = 0; rb < 4; ++rb)
      for (int kc = 0; kc < 2; ++kc)
        fr[rb][kc] = *(const half8*)&Wh[(lane15 + 16 * rb) * 80 + 32 * kc + 8 * quad];
    float4v D[4][4];
    for (int mb = 0; mb < 4; ++mb) for (int nb = 0; nb < 4; ++nb) D[mb][nb] = (float4v){0.f, 0.f, 0.f, 0.f};
    for (int kc = 0; kc < 2; ++kc)
      for (int mb = 0; mb < 4; ++mb)
        for (int nb = 0; nb < 4; ++nb)
          D[mb][nb] = __builtin_amdgcn_mfma_f32_16x16x32_f16(fr[mb][kc], fr[nb][kc], D[mb][nb], 0, 0, 0);
    for (int it = 0; it < 8; ++it) {
      float mx = 0.f;
      for (int mb = 0; mb < 4; ++mb) for (int nb = 0; nb < 4; ++nb) for (int r = 0; r < 4; ++r)
        mx = fmaxf(mx, fabsf(D[mb][nb][r]));
      for (int d = 1; d < 64; d <<= 1) mx = fmaxf(mx, __shfl_xor(mx, d, 64));
      float rs = 1.f / mx;
      for (int mb = 0; mb < 4; ++mb) for (int nb = 0; nb < 4; ++nb) for (int r = 0; r < 4; ++r)
        Gh[(4 * quad + r + 16 * mb) * 80 + lane15 + 16 * nb] = (_Float16)(D[mb][nb][r] * rs);
      __syncthreads();
      if (it == 7) break;
      for (int rb = 0; rb < 4; ++rb)
        for (int kc = 0; kc < 2; ++kc)
          fr[rb][kc] = *(const half8*)&Gh[(lane15 + 16 * rb) * 80 + 32 * kc + 8 * quad];
      for (int mb = 0; mb < 4; ++mb) for (int nb = 0; nb < 4; ++nb) D[mb][nb] = (float4v){0.f, 0.f, 0.f, 0.f};
      for (int kc = 0; kc < 2; ++kc)
        for (int mb = 0; mb < 4; ++mb)
          for (int nb = 0; nb < 4; ++nb)
            D[mb][nb] = __builtin_amdgcn_mfma_f32_16x16x32_f16(fr[mb][kc], fr[nb][kc], D[mb][nb], 0, 0, 0);
      __syncthreads();
    }
    float u = 0.f;
    for (int c = 0; c < 64; ++c) u += (float)Gh[t * 80 + c];
    float z = 0.f;
    for (int i2 = 0; i2 < 64; ++i2) z += Wl[i2 * 64 + t] * __shfl(u, i2, 64);
    float nu = z * z, de = u * u;
    for (int d = 1; d < 64; d <<= 1) { nu += __shfl_xor(nu, d, 64); de += __shfl_xor(de, d, 64); }
    if (t == 0) sig[2] = sqrtf(nu / de);
  }
}

// ---------------------------------------------------------------- k_fgh
__global__ __launch_bounds__(256) void k_fgh(const float* __restrict__ x,
                                             const float* __restrict__ Wq, const float* __restrict__ bq,
                                             const float* __restrict__ Wk, const float* __restrict__ bk,
                                             const float* __restrict__ Wv, const float* __restrict__ bv,
                                             const float* __restrict__ sig,
                                             _Float16* __restrict__ K16,
                                             _Float16* __restrict__ Q16,
                                             _Float16* __restrict__ VT16,
                                             unsigned* __restrict__ maxKu) {
  __shared__ _Float16 Wsh[80 * 64];
  __shared__ float bsh[80];
  const int t = threadIdx.x;
  const float iq = LOG2E / sig[0], ik = 1.0f / sig[1], iv = 1.0f / sig[2];
  for (int idx = t; idx < 80 * 64; idx += 256) {
    const int m = idx >> 6, c = idx & 63;
    float v;
    if (m < 8)       v = Wq[m * 64 + c] * iq;
    else if (m < 16) v = Wk[(m - 8) * 64 + c] * ik;
    else             v = Wv[(m - 16) * 64 + c] * iv;
    Wsh[idx] = (_Float16)v;
  }
  if (t < 80) {
    float v;
    if (t < 8)       v = bq[t] * LOG2E;
    else if (t < 16) v = bk[t - 8];
    else             v = bv[t - 16];
    bsh[t] = v;
  }
  __syncthreads();
  const int wave = t >> 6;
  const int lane = t & 63;
  const int lane15 = lane & 15, quad = lane >> 4;
  const int tile = blockIdx.x * 4 + wave;
  const int b = tile / 576;
  const int n = (tile % 576) * 16 + lane15;
  half8 wf[5][2];
  for (int mb = 0; mb < 5; ++mb)
    for (int kc = 0; kc < 2; ++kc)
      wf[mb][kc] = *(const half8*)&Wsh[(lane15 + 16 * mb) * 64 + 32 * kc + 8 * quad];
  float4v acc[5];
  for (int mb = 0; mb < 5; ++mb) acc[mb] = *(const float4v*)&bsh[16 * mb + 4 * quad];
  const float* xb = x + (size_t)b * N_C * N_PIX;
  for (int kc = 0; kc < 2; ++kc) {
    half8 bf;
    for (int j = 0; j < 8; ++j)
      bf[j] = (_Float16)xb[(size_t)(32 * kc + 8 * quad + j) * N_PIX + n];
    for (int mb = 0; mb < 5; ++mb)
      acc[mb] = __builtin_amdgcn_mfma_f32_16x16x32_f16(wf[mb][kc], bf, acc[mb], 0, 0, 0);
  }
  {
    _Float16* dstK = K16 + ((size_t)b * N_PIX + n) * 8;
    _Float16* dstQ = Q16 + ((size_t)b * N_PIX + n) * 8;
    for (int r = 0; r < 4; ++r) {
      const int m = 4 * quad + r;
      const _Float16 v = (_Float16)acc[0][r];
      if (m < 8) dstK[m] = v; else dstQ[m - 8] = v;
    }
  }
  for (int mb = 1; mb < 5; ++mb)
    for (int r = 0; r < 4; ++r) {
      const int c = 4 * quad + r + 16 * (mb - 1);
      VT16[((size_t)b * N_C + c) * N_PIX + n] = (_Float16)acc[mb][r];
    }
  float sq = 0.f;
  if (quad < 2)
    for (int r = 0; r < 4; ++r) sq += acc[0][r] * acc[0][r];
  sq += __shfl_xor(sq, 16, 64);
  for (int d = 1; d < 64; d <<= 1) sq = fmaxf(sq, __shfl_xor(sq, d, 64));
  if (lane == 0) atomicMax(&maxKu[b], __float_as_uint(sq));
}

// ---------------------------------------------------------------- k_attn
// 576 blocks x 4 waves, 32-query tile; round r (0..71): wave w owns keys
// [128r+32w, +32). No barriers in the loop. Per-wave LDS region 5120 halves:
//   [0..2047] V slot0 (64ch x 32keys, swizzled)  [2048..4095] V slot1
//   [4096..4607] K slot0 (32 rows x 8, + dup)    [4608..5119] K slot1
// Epilogue Osh(64x17 f32)+Lsh aliased at region start (after vmcnt(0) drain).

__device__ __forceinline__ void gload16(const _Float16* g, _Float16* l) {
  __builtin_amdgcn_global_load_lds(
      (const __attribute__((address_space(1))) void*)g,
      (__attribute__((address_space(3))) void*)l, 16, 0, 0);
}
#define VMWAIT5() asm volatile("s_waitcnt vmcnt(5)" ::: "memory")

__global__ __launch_bounds__(256, 3) void k_attn(const _Float16* __restrict__ K16,
                                                 const _Float16* __restrict__ Q16,
                                                 const _Float16* __restrict__ VT16,
                                                 const unsigned* __restrict__ maxKu,
                                                 const float* __restrict__ x,
                                                 const float* __restrict__ gamma,
                                                 float* __restrict__ out) {
  __shared__ __align__(16) _Float16 SM[4][5120];   // 40960 B -> 3-4 blocks/CU
  const int wave = threadIdx.x >> 6;
  const int lane = threadIdx.x & 63;
  const int q31 = lane & 31, hi = lane >> 5;
  const int tile = blockIdx.x;            // 0..575
  const int b = tile / 288;
  const int jb = (tile % 288) * 32;
  const float gm = gamma[0];
  const _Float16* Kb = K16 + (size_t)b * N_PIX * 8;
  const _Float16* Vb = VT16 + (size_t)b * N_C * N_PIX;
  _Float16* Rg = SM[wave];
  // staging lane mapping: per DMA-instr i, lane covers channel 16i+(lane>>2),
  // LDS granule kk=lane&3; source granule = kk ^ (c&3) = kk ^ ((lane>>2)&3).
  const int cl = lane >> 2, kk = lane & 3;
  const int gsw = (kk ^ (cl & 3)) * 8;
  // V read offsets (per lane, loop-invariant): tile t, kstep s ->
  // c = 32t + q31, granule g = 2s+hi, slot = g ^ (q31&3).
  const int vq = q31 * 32;
  const int voff00 = vq + (((0 + hi) ^ (q31 & 3)) << 3);          // t=0,s=0
  const int voff01 = vq + (((2 + hi) ^ (q31 & 3)) << 3);          // t=0,s=1
  const int voff10 = 1024 + voff00;                               // t=1,s=0
  const int voff11 = 1024 + voff01;                               // t=1,s=1

  // Q B-frag: n=q31, k=8*hi+j; hi=0 lanes real (dims 0-7), hi=1 zero.
  half8 qf = {};
  if (hi == 0) qf = *(const half8*)(Q16 + ((size_t)b * N_PIX + jb + q31) * 8);
  const float maxK = sqrtf(__uint_as_float(maxKu[b]));
  float nq = 0.f;
#pragma unroll
  for (int j = 0; j < 8; ++j) nq += (float)qf[j] * (float)qf[j];
  nq += __shfl_xor(nq, 32, 64);           // both halves get the query norm
  const float M = sqrtf(nq) * maxK - EXP_SHIFT;
  float16v sinit;
#pragma unroll
  for (int r2 = 0; r2 < 16; ++r2) sinit[r2] = -M;

  float16v acc0 = {}, acc1 = {};
  float ls = 0.f;

#define STAGE(SLOT, I0)                                                          \
  {                                                                              \
    const int _i = (I0);                                                         \
    gload16(Kb + (size_t)(_i + q31) * 8, Rg + 4096 + (SLOT) * 512);              \
    gload16(Vb + (size_t)cl * N_PIX + _i + gsw,        Rg + (SLOT) * 2048);      \
    gload16(Vb + (size_t)(16 + cl) * N_PIX + _i + gsw, Rg + (SLOT) * 2048 + 512);\
    gload16(Vb + (size_t)(32 + cl) * N_PIX + _i + gsw, Rg + (SLOT) * 2048 + 1024);\
    gload16(Vb + (size_t)(48 + cl) * N_PIX + _i + gsw, Rg + (SLOT) * 2048 + 1536);\
  }

  STAGE(0, 32 * wave)

#pragma unroll 1
  for (int r = 0; r < 72; ++r) {
    const int slot = r & 1, nslot = slot ^ 1;
    const int i1 = (r < 71) ? (128 * (r + 1) + 32 * wave) : (128 * 71 + 32 * wave);
    STAGE(nslot, i1)
    VMWAIT5();
    // K A-frag: m=key=q31, k=8*hi+j; hi=1 lanes must be ZERO (dims 8-15).
    half8 kf = *(const half8*)&Rg[4096 + slot * 512 + q31 * 8];
    if (hi) kf = (half8){};
    // S = K x Q - M  (C preloaded with -M)
    float16v s = __builtin_amdgcn_mfma_f32_32x32x16_f16(kf, qf, sinit, 0, 0, 0);
    // p = exp2(s); f32 lsum; pack pairs (keys consecutive within reg quads)
    int pk[8];
#pragma unroll
    for (int u = 0; u < 8; ++u) {
      const float p0 = __builtin_amdgcn_exp2f(s[2 * u]);
      const float p1 = __builtin_amdgcn_exp2f(s[2 * u + 1]);
      ls += p0 + p1;
      pk[u] = __builtin_bit_cast(int, __builtin_amdgcn_cvt_pkrtz(p0, p1));
    }
    // P C-layout -> B-layout via lane<->lane^32 exchange.
    const int t0 = hi ? pk[0] : pk[2];
    const int t1 = hi ? pk[1] : pk[3];
    const int t2 = hi ? pk[4] : pk[6];
    const int t3 = hi ? pk[5] : pk[7];
    const int x0 = __shfl_xor(t0, 32, 64);
    const int x1 = __shfl_xor(t1, 32, 64);
    const int x2 = __shfl_xor(t2, 32, 64);
    const int x3 = __shfl_xor(t3, 32, 64);
    int4v B0i, B1i;
    B0i[0] = hi ? x0 : pk[0];  B0i[1] = hi ? x1 : pk[1];
    B0i[2] = hi ? pk[2] : x0;  B0i[3] = hi ? pk[3] : x1;
    B1i[0] = hi ? x2 : pk[4];  B1i[1] = hi ? x3 : pk[5];
    B1i[2] = hi ? pk[6] : x2;  B1i[3] = hi ? pk[7] : x3;
    const half8 P0 = __builtin_bit_cast(half8, B0i);
    const half8 P1 = __builtin_bit_cast(half8, B1i);
    // V A-frags (m=channel, k=key) from swizzled LDS.
    const _Float16* Vs = Rg + slot * 2048;
    const half8 v00 = *(const half8*)&Vs[voff00];
    const half8 v01 = *(const half8*)&Vs[voff01];
    const half8 v10 = *(const half8*)&Vs[voff10];
    const half8 v11 = *(const half8*)&Vs[voff11];
    acc0 = __builtin_amdgcn_mfma_f32_32x32x16_f16(v00, P0, acc0, 0, 0, 0);
    acc0 = __builtin_amdgcn_mfma_f32_32x32x16_f16(v01, P1, acc0, 0, 0, 0);
    acc1 = __builtin_amdgcn_mfma_f32_32x32x16_f16(v10, P0, acc1, 0, 0, 0);
    acc1 = __builtin_amdgcn_mfma_f32_32x32x16_f16(v11, P1, acc1, 0, 0, 0);
  }
#undef STAGE
  asm volatile("s_waitcnt vmcnt(0)" ::: "memory");  // drain dangling staging

  // ---- epilogue: alias Osh/Lsh into THIS WAVE's region.
  float* Ow = (float*)Rg;                // 64 x 17 f32
  float* Lw = (float*)Rg + 1100;         // 32 f32
  ls += __shfl_xor(ls, 32, 64);          // full 2304-key sum per query
  if (hi == 0) Lw[q31] = ls;
#pragma unroll
  for (int r2 = 0; r2 < 16; ++r2) Ow[lane * 17 + r2] = acc0[r2];
  __syncthreads();
  float ltot = 0.f;
#pragma unroll
  for (int w = 0; w < 4; ++w) ltot += ((const float*)SM[w])[1100 + q31];
  const float inv = gm / ltot;
  const float* xb = x + (size_t)b * N_C * N_PIX;
  float* ob = out + (size_t)b * N_C * N_PIX;
#pragma unroll
  for (int r2 = 0; r2 < 16; ++r2) {
    float osum = 0.f;
#pragma unroll
    for (int w = 0; w < 4; ++w) osum += ((const float*)SM[w])[lane * 17 + r2];
    const int c = (r2 & 3) + 8 * (r2 >> 2) + 4 * hi;
    const size_t idx = (size_t)c * N_PIX + jb + q31;
    ob[idx] = osum * inv + xb[idx];
  }
  __syncthreads();
#pragma unroll
  for (int r2 = 0; r2 < 16; ++r2) Ow[lane * 17 + r2] = acc1[r2];
  __syncthreads();
#pragma unroll
  for (int r2 = 0; r2 < 16; ++r2) {
    float osum = 0.f;
#pragma unroll
    for (int w = 0; w < 4; ++w) osum += ((const float*)SM[w])[lane * 17 + r2];
    const int c = 32 + (r2 & 3) + 8 * (r2 >> 2) + 4 * hi;
    const size_t idx = (size_t)c * N_PIX + jb + q31;
    ob[idx] = osum * inv + xb[idx];
  }
}

// ---------------------------------------------------------------- launch
extern "C" void kernel_launch(void* const* d_in, const int* in_sizes, int n_in,
                              void* d_out, int out_size, void* d_ws, size_t ws_size,
                              hipStream_t stream) {
  const float* x     = (const float*)d_in[0];
  const float* Wq    = (const float*)d_in[1];
  const float* bq    = (const float*)d_in[2];
  const float* Wk    = (const float*)d_in[3];
  const float* bk    = (const float*)d_in[4];
  const float* Wv    = (const float*)d_in[5];
  const float* bv    = (const float*)d_in[6];
  const float* gamma = (const float*)d_in[7];
  float* out = (float*)d_out;

  char* ws = (char*)d_ws;
  float*    sig   = (float*)ws;                       // 4 floats
  unsigned* maxKu = (unsigned*)(ws + 16);             // 2 uints (float bits, >=0)
  _Float16* K16   = (_Float16*)(ws + 10752);          // 2*9216*8
  _Float16* Q16   = (_Float16*)(ws + 10752 + 294912); // 2*9216*8
  _Float16* VT16  = (_Float16*)(ws + 10752 + 2 * 294912); // 2*64*9216

  hipLaunchKernelGGL(k_sigma, dim3(3), dim3(64), 0, stream, Wq, Wk, Wv, sig, maxKu);
  hipLaunchKernelGGL(k_fgh, dim3(288), dim3(256), 0, stream,
                     x, Wq, bq, Wk, bk, Wv, bv, sig, K16, Q16, VT16, maxKu);
  hipLaunchKernelGGL(k_attn, dim3(576), dim3(256), 0, stream, K16, Q16, VT16, maxKu, x, gamma, out);
}

// Round 12
// 171.911 us; speedup vs baseline: 1.2854x; 1.0178x over previous
//
#include <hip/hip_runtime.h>

// SelfAttention (SAGAN-style) on MI355X.
// B=2, C=64, C8=8, H=W=96, N=9216.  out = gamma * Attn(g,f,h) + x
//   K = f = (Wq/sq) x + bq   (pre-scaled by log2e; softmax in exp2 domain)
//   Q = g = (Wk/sk) x + bk
//   V = h = (Wv/sv) x + bv
// softmax over keys i; head_dim 8 (zero-padded), dv=64.
//
// R12: occupancy + swizzle fix. R11 evidence: conflicts doubled (my V swizzle
// used g^(c&3); correct is g^((c>>1)&3) - lanes c,c+4 collided), and the
// serial round chain (~500cyc: dsK->S-MFMA->exp2->shfl->PV) is exposed at
// 2.25 waves/SIMD because the 576-block GRID caps occupancy. Now:
//  (1) swizzle slot = g ^ ((c>>1)&3) both sides -> conflict-free V reads.
//  (2) 2-way key split across blocks: 1152 blocks x 36 rounds, partial
//      O (f32, no divide) + partial l to workspace (12.6 MB).
//  (3) k_merge: out = gm*(O0+O1)/(l0+l1) + x, coalesced.
// Numerics unchanged (M = |Q|*max|K'| - 12, f16 P, f32 lsum).

#define N_PIX 9216
#define N_B   2
#define N_C   64

typedef _Float16 half8  __attribute__((ext_vector_type(8)));
typedef float    float4v __attribute__((ext_vector_type(4)));
typedef float    float16v __attribute__((ext_vector_type(16)));
typedef int      int4v  __attribute__((ext_vector_type(4)));

#define LOG2E 1.44269504088896340736f
#define EXP_SHIFT 12.0f

// ---------------------------------------------------------------- k_sigma
__global__ __launch_bounds__(64) void k_sigma(const float* __restrict__ Wq,
                                              const float* __restrict__ Wk,
                                              const float* __restrict__ Wv,
                                              float* __restrict__ sig,
                                              unsigned* __restrict__ maxKu) {
  __shared__ float G8[8][8];
  __shared__ float Wl[64 * 64];
  __shared__ _Float16 Wh[64 * 80];
  __shared__ _Float16 Gh[64 * 80];
  const int t = threadIdx.x;
  const int mat = blockIdx.x;
  if (mat == 0 && t < 2) maxKu[t] = 0u;
  if (mat < 2) {
    const float* W = (mat == 0) ? Wq : Wk;
    const int i = t >> 3, j = t & 7;
    float g = 0.f;
    for (int c = 0; c < 64; ++c) g += W[i * 64 + c] * W[j * 64 + c];
    G8[i][j] = g;
    __syncthreads();
    const int L = t & 7;
    float G0[8], Gr[8];
    for (int k = 0; k < 8; ++k) { G0[k] = G8[L][k]; Gr[k] = G0[k]; }
    for (int it = 0; it < 8; ++it) {
      float g2[8] = {0, 0, 0, 0, 0, 0, 0, 0};
      for (int k = 0; k < 8; ++k) {
        float gik = Gr[k];
        for (int jj = 0; jj < 8; ++jj) g2[jj] += gik * __shfl(Gr[jj], k, 64);
      }
      float mx = 0.f;
      for (int jj = 0; jj < 8; ++jj) mx = fmaxf(mx, fabsf(g2[jj]));
      for (int d = 1; d < 8; d <<= 1) mx = fmaxf(mx, __shfl_xor(mx, d, 64));
      float r = 1.f / mx;
      for (int jj = 0; jj < 8; ++jj) Gr[jj] = g2[jj] * r;
    }
    float u = 0.f;
    for (int jj = 0; jj < 8; ++jj) u += Gr[jj];
    float y = 0.f;
    for (int k = 0; k < 8; ++k) y += G0[k] * __shfl(u, k, 64);
    float nu = u * y, de = u * u;
    for (int d = 1; d < 8; d <<= 1) { nu += __shfl_xor(nu, d, 64); de += __shfl_xor(de, d, 64); }
    if (t == 0) sig[mat] = sqrtf(nu / de);
  } else {
    for (int idx = t; idx < 4096; idx += 64) Wl[idx] = Wv[idx];
    __syncthreads();
    for (int idx = t; idx < 4096; idx += 64) Wh[(idx >> 6) * 80 + (idx & 63)] = (_Float16)Wl[idx];
    __syncthreads();
    const int lane15 = t & 15, quad = t >> 4;
    half8 fr[4][2];
    for (int rb = 0; rb < 4; ++rb)
      for (int kc = 0; kc < 2; ++kc)
        fr[rb][kc] = *(const half8*)&Wh[(lane15 + 16 * rb) * 80 + 32 * kc + 8 * quad];
    float4v D[4][4];
    for (int mb = 0; mb < 4; ++mb) for (int nb = 0; nb < 4; ++nb) D[mb][nb] = (float4v){0.f, 0.f, 0.f, 0.f};
    for (int kc = 0; kc < 2; ++kc)
      for (int mb = 0; mb < 4; ++mb)
        for (int nb = 0; nb < 4; ++nb)
          D[mb][nb] = __builtin_amdgcn_mfma_f32_16x16x32_f16(fr[mb][kc], fr[nb][kc], D[mb][nb], 0, 0, 0);
    for (int it = 0; it < 8; ++it) {
      float mx = 0.f;
      for (int mb = 0; mb < 4; ++mb) for (int nb = 0; nb < 4; ++nb) for (int r = 0; r < 4; ++r)
        mx = fmaxf(mx, fabsf(D[mb][nb][r]));
      for (int d = 1; d < 64; d <<= 1) mx = fmaxf(mx, __shfl_xor(mx, d, 64));
      float rs = 1.f / mx;
      for (int mb = 0; mb < 4; ++mb) for (int nb = 0; nb < 4; ++nb) for (int r = 0; r < 4; ++r)
        Gh[(4 * quad + r + 16 * mb) * 80 + lane15 + 16 * nb] = (_Float16)(D[mb][nb][r] * rs);
      __syncthreads();
      if (it == 7) break;
      for (int rb = 0; rb < 4; ++rb)
        for (int kc = 0; kc < 2; ++kc)
          fr[rb][kc] = *(const half8*)&Gh[(lane15 + 16 * rb) * 80 + 32 * kc + 8 * quad];
      for (int mb = 0; mb < 4; ++mb) for (int nb = 0; nb < 4; ++nb) D[mb][nb] = (float4v){0.f, 0.f, 0.f, 0.f};
      for (int kc = 0; kc < 2; ++kc)
        for (int mb = 0; mb < 4; ++mb)
          for (int nb = 0; nb < 4; ++nb)
            D[mb][nb] = __builtin_amdgcn_mfma_f32_16x16x32_f16(fr[mb][kc], fr[nb][kc], D[mb][nb], 0, 0, 0);
      __syncthreads();
    }
    float u = 0.f;
    for (int c = 0; c < 64; ++c) u += (float)Gh[t * 80 + c];
    float z = 0.f;
    for (int i2 = 0; i2 < 64; ++i2) z += Wl[i2 * 64 + t] * __shfl(u, i2, 64);
    float nu = z * z, de = u * u;
    for (int d = 1; d < 64; d <<= 1) { nu += __shfl_xor(nu, d, 64); de += __shfl_xor(de, d, 64); }
    if (t == 0) sig[2] = sqrtf(nu / de);
  }
}

// ---------------------------------------------------------------- k_fgh
__global__ __launch_bounds__(256) void k_fgh(const float* __restrict__ x,
                                             const float* __restrict__ Wq, const float* __restrict__ bq,
                                             const float* __restrict__ Wk, const float* __restrict__ bk,
                                             const float* __restrict__ Wv, const float* __restrict__ bv,
                                             const float* __restrict__ sig,
                                             _Float16* __restrict__ K16,
                                             _Float16* __restrict__ Q16,
                                             _Float16* __restrict__ VT16,
                                             unsigned* __restrict__ maxKu) {
  __shared__ _Float16 Wsh[80 * 64];
  __shared__ float bsh[80];
  const int t = threadIdx.x;
  const float iq = LOG2E / sig[0], ik = 1.0f / sig[1], iv = 1.0f / sig[2];
  for (int idx = t; idx < 80 * 64; idx += 256) {
    const int m = idx >> 6, c = idx & 63;
    float v;
    if (m < 8)       v = Wq[m * 64 + c] * iq;
    else if (m < 16) v = Wk[(m - 8) * 64 + c] * ik;
    else             v = Wv[(m - 16) * 64 + c] * iv;
    Wsh[idx] = (_Float16)v;
  }
  if (t < 80) {
    float v;
    if (t < 8)       v = bq[t] * LOG2E;
    else if (t < 16) v = bk[t - 8];
    else             v = bv[t - 16];
    bsh[t] = v;
  }
  __syncthreads();
  const int wave = t >> 6;
  const int lane = t & 63;
  const int lane15 = lane & 15, quad = lane >> 4;
  const int tile = blockIdx.x * 4 + wave;
  const int b = tile / 576;
  const int n = (tile % 576) * 16 + lane15;
  half8 wf[5][2];
  for (int mb = 0; mb < 5; ++mb)
    for (int kc = 0; kc < 2; ++kc)
      wf[mb][kc] = *(const half8*)&Wsh[(lane15 + 16 * mb) * 64 + 32 * kc + 8 * quad];
  float4v acc[5];
  for (int mb = 0; mb < 5; ++mb) acc[mb] = *(const float4v*)&bsh[16 * mb + 4 * quad];
  const float* xb = x + (size_t)b * N_C * N_PIX;
  for (int kc = 0; kc < 2; ++kc) {
    half8 bf;
    for (int j = 0; j < 8; ++j)
      bf[j] = (_Float16)xb[(size_t)(32 * kc + 8 * quad + j) * N_PIX + n];
    for (int mb = 0; mb < 5; ++mb)
      acc[mb] = __builtin_amdgcn_mfma_f32_16x16x32_f16(wf[mb][kc], bf, acc[mb], 0, 0, 0);
  }
  {
    _Float16* dstK = K16 + ((size_t)b * N_PIX + n) * 8;
    _Float16* dstQ = Q16 + ((size_t)b * N_PIX + n) * 8;
    for (int r = 0; r < 4; ++r) {
      const int m = 4 * quad + r;
      const _Float16 v = (_Float16)acc[0][r];
      if (m < 8) dstK[m] = v; else dstQ[m - 8] = v;
    }
  }
  for (int mb = 1; mb < 5; ++mb)
    for (int r = 0; r < 4; ++r) {
      const int c = 4 * quad + r + 16 * (mb - 1);
      VT16[((size_t)b * N_C + c) * N_PIX + n] = (_Float16)acc[mb][r];
    }
  float sq = 0.f;
  if (quad < 2)
    for (int r = 0; r < 4; ++r) sq += acc[0][r] * acc[0][r];
  sq += __shfl_xor(sq, 16, 64);
  for (int d = 1; d < 64; d <<= 1) sq = fmaxf(sq, __shfl_xor(sq, d, 64));
  if (lane == 0) atomicMax(&maxKu[b], __float_as_uint(sq));
}

// ---------------------------------------------------------------- k_attn
// 1152 blocks: tile = b*576 + jt*2 + h; block covers keys [4608h, +4608),
// 36 rounds of 128 keys (wave w owns 32). Writes partial O (f32, undivided)
// and partial l to workspace. Per-wave LDS region 5120 halves:
//   [0..2047] V slot0 (64ch x 32keys, swizzled g^((c>>1)&3))
//   [2048..4095] V slot1;  [4096..4607] K slot0;  [4608..5119] K slot1.

__device__ __forceinline__ void gload16(const _Float16* g, _Float16* l) {
  __builtin_amdgcn_global_load_lds(
      (const __attribute__((address_space(1))) void*)g,
      (__attribute__((address_space(3))) void*)l, 16, 0, 0);
}
#define VMWAIT5() asm volatile("s_waitcnt vmcnt(5)" ::: "memory")

__global__ __launch_bounds__(256, 4) void k_attn(const _Float16* __restrict__ K16,
                                                 const _Float16* __restrict__ Q16,
                                                 const _Float16* __restrict__ VT16,
                                                 const unsigned* __restrict__ maxKu,
                                                 float* __restrict__ Opart,
                                                 float* __restrict__ Lpart) {
  __shared__ __align__(16) _Float16 SM[4][5120];   // 40960 B -> 4 blocks/CU
  const int wave = threadIdx.x >> 6;
  const int lane = threadIdx.x & 63;
  const int q31 = lane & 31, hi = lane >> 5;
  const int tile = blockIdx.x;            // 0..1151
  const int b = tile / 576;
  const int rm = tile % 576;
  const int jb = (rm >> 1) * 32;
  const int h = rm & 1;
  const int kh = h * (N_PIX / 2);         // this block's key range base
  const _Float16* Kb = K16 + (size_t)b * N_PIX * 8;
  const _Float16* Vb = VT16 + (size_t)b * N_C * N_PIX;
  _Float16* Rg = SM[wave];
  // staging: instr i covers channel c=16i+cl, cl=lane>>2, LDS granule kk=lane&3,
  // source granule = kk ^ ((c>>1)&3) = kk ^ ((cl>>1)&3)   [8i doesn't touch bit1-2]
  const int cl = lane >> 2, kk = lane & 3;
  const int gsw = (kk ^ ((cl >> 1) & 3)) * 8;
  // read offsets: channel row 32c; granule g at slot g ^ ((c>>1)&3); c=q31 / 32+q31
  const int vx = (q31 >> 1) & 3;
  const int voff00 = q31 * 32 + ((hi ^ vx) << 3);
  const int voff01 = q31 * 32 + (((2 + hi) ^ vx) << 3);
  const int voff10 = 1024 + voff00;
  const int voff11 = 1024 + voff01;

  // Q B-frag: n=q31, k=8*hi+j; hi=0 lanes real (dims 0-7), hi=1 zero.
  half8 qf = {};
  if (hi == 0) qf = *(const half8*)(Q16 + ((size_t)b * N_PIX + jb + q31) * 8);
  const float maxK = sqrtf(__uint_as_float(maxKu[b]));
  float nq = 0.f;
#pragma unroll
  for (int j = 0; j < 8; ++j) nq += (float)qf[j] * (float)qf[j];
  nq += __shfl_xor(nq, 32, 64);
  const float M = sqrtf(nq) * maxK - EXP_SHIFT;
  float16v sinit;
#pragma unroll
  for (int r2 = 0; r2 < 16; ++r2) sinit[r2] = -M;

  float16v acc0 = {}, acc1 = {};
  float ls = 0.f;

#define STAGE(SLOT, I0)                                                          \
  {                                                                              \
    const int _i = (I0);                                                         \
    gload16(Kb + (size_t)(_i + q31) * 8, Rg + 4096 + (SLOT) * 512);              \
    gload16(Vb + (size_t)cl * N_PIX + _i + gsw,        Rg + (SLOT) * 2048);      \
    gload16(Vb + (size_t)(16 + cl) * N_PIX + _i + gsw, Rg + (SLOT) * 2048 + 512);\
    gload16(Vb + (size_t)(32 + cl) * N_PIX + _i + gsw, Rg + (SLOT) * 2048 + 1024);\
    gload16(Vb + (size_t)(48 + cl) * N_PIX + _i + gsw, Rg + (SLOT) * 2048 + 1536);\
  }

  STAGE(0, kh + 32 * wave)

#pragma unroll 1
  for (int r = 0; r < 36; ++r) {
    const int slot = r & 1, nslot = slot ^ 1;
    const int i1 = kh + ((r < 35) ? (128 * (r + 1) + 32 * wave) : (128 * 35 + 32 * wave));
    STAGE(nslot, i1)
    VMWAIT5();
    // K A-frag: m=key=q31, k=8*hi+j; hi=1 lanes must be ZERO (dims 8-15).
    half8 kf = *(const half8*)&Rg[4096 + slot * 512 + q31 * 8];
    if (hi) kf = (half8){};
    float16v s = __builtin_amdgcn_mfma_f32_32x32x16_f16(kf, qf, sinit, 0, 0, 0);
    int pk[8];
#pragma unroll
    for (int u = 0; u < 8; ++u) {
      const float p0 = __builtin_amdgcn_exp2f(s[2 * u]);
      const float p1 = __builtin_amdgcn_exp2f(s[2 * u + 1]);
      ls += p0 + p1;
      pk[u] = __builtin_bit_cast(int, __builtin_amdgcn_cvt_pkrtz(p0, p1));
    }
    // P C-layout -> B-layout via lane<->lane^32 exchange (R11-verified).
    const int t0 = hi ? pk[0] : pk[2];
    const int t1 = hi ? pk[1] : pk[3];
    const int t2 = hi ? pk[4] : pk[6];
    const int t3 = hi ? pk[5] : pk[7];
    const int x0 = __shfl_xor(t0, 32, 64);
    const int x1 = __shfl_xor(t1, 32, 64);
    const int x2 = __shfl_xor(t2, 32, 64);
    const int x3 = __shfl_xor(t3, 32, 64);
    int4v B0i, B1i;
    B0i[0] = hi ? x0 : pk[0];  B0i[1] = hi ? x1 : pk[1];
    B0i[2] = hi ? pk[2] : x0;  B0i[3] = hi ? pk[3] : x1;
    B1i[0] = hi ? x2 : pk[4];  B1i[1] = hi ? x3 : pk[5];
    B1i[2] = hi ? pk[6] : x2;  B1i[3] = hi ? pk[7] : x3;
    const half8 P0 = __builtin_bit_cast(half8, B0i);
    const half8 P1 = __builtin_bit_cast(half8, B1i);
    const _Float16* Vs = Rg + slot * 2048;
    const half8 v00 = *(const half8*)&Vs[voff00];
    const half8 v01 = *(const half8*)&Vs[voff01];
    const half8 v10 = *(const half8*)&Vs[voff10];
    const half8 v11 = *(const half8*)&Vs[voff11];
    acc0 = __builtin_amdgcn_mfma_f32_32x32x16_f16(v00, P0, acc0, 0, 0, 0);
    acc0 = __builtin_amdgcn_mfma_f32_32x32x16_f16(v01, P1, acc0, 0, 0, 0);
    acc1 = __builtin_amdgcn_mfma_f32_32x32x16_f16(v10, P0, acc1, 0, 0, 0);
    acc1 = __builtin_amdgcn_mfma_f32_32x32x16_f16(v11, P1, acc1, 0, 0, 0);
  }
#undef STAGE
  asm volatile("s_waitcnt vmcnt(0)" ::: "memory");  // drain dangling staging

  // ---- cross-wave merge in own region, then write partials (undivided).
  float* Ow = (float*)Rg;                // 64 x 17 f32
  float* Lw = (float*)Rg + 1100;         // 32 f32
  ls += __shfl_xor(ls, 32, 64);
  if (hi == 0) Lw[q31] = ls;
#pragma unroll
  for (int r2 = 0; r2 < 16; ++r2) Ow[lane * 17 + r2] = acc0[r2];
  __syncthreads();
  float ltot = 0.f;
#pragma unroll
  for (int w = 0; w < 4; ++w) ltot += ((const float*)SM[w])[1100 + q31];
  float* Op = Opart + (size_t)tile * 2048;
  if (wave == 0 && hi == 0) Lpart[tile * 32 + q31] = ltot;
#pragma unroll
  for (int r2 = 0; r2 < 16; ++r2) {
    float osum = 0.f;
#pragma unroll
    for (int w = 0; w < 4; ++w) osum += ((const float*)SM[w])[lane * 17 + r2];
    const int c = (r2 & 3) + 8 * (r2 >> 2) + 4 * hi;
    Op[c * 32 + q31] = osum;
  }
  __syncthreads();
#pragma unroll
  for (int r2 = 0; r2 < 16; ++r2) Ow[lane * 17 + r2] = acc1[r2];
  __syncthreads();
#pragma unroll
  for (int r2 = 0; r2 < 16; ++r2) {
    float osum = 0.f;
#pragma unroll
    for (int w = 0; w < 4; ++w) osum += ((const float*)SM[w])[lane * 17 + r2];
    const int c = 32 + (r2 & 3) + 8 * (r2 >> 2) + 4 * hi;
    Op[c * 32 + q31] = osum;
  }
}

// ---------------------------------------------------------------- k_merge
// 576 blocks (b, jt): out = gm*(O0+O1)/(l0+l1) + x.
__global__ __launch_bounds__(256) void k_merge(const float* __restrict__ Opart,
                                               const float* __restrict__ Lpart,
                                               const float* __restrict__ x,
                                               const float* __restrict__ gamma,
                                               float* __restrict__ out) {
  __shared__ float Ls[32];
  const int t2 = blockIdx.x;              // 0..575
  const int b = t2 / 288, jt = t2 % 288;
  const int jb = jt * 32;
  const int tile0 = b * 576 + jt * 2;
  const float gm = gamma[0];
  const int t = threadIdx.x;
  if (t < 32) Ls[t] = Lpart[tile0 * 32 + t] + Lpart[(tile0 + 1) * 32 + t];
  __syncthreads();
  const float* O0 = Opart + (size_t)tile0 * 2048;
  const float* O1 = O0 + 2048;
  const float* xb = x + (size_t)b * N_C * N_PIX;
  float* ob = out + (size_t)b * N_C * N_PIX;
#pragma unroll
  for (int k = 0; k < 8; ++k) {
    const int idx = t + 256 * k;
    const int c = idx >> 5, q = idx & 31;
    const size_t gi = (size_t)c * N_PIX + jb + q;
    ob[gi] = gm * (O0[idx] + O1[idx]) / Ls[q] + xb[gi];
  }
}

// ---------------------------------------------------------------- launch
extern "C" void kernel_launch(void* const* d_in, const int* in_sizes, int n_in,
                              void* d_out, int out_size, void* d_ws, size_t ws_size,
                              hipStream_t stream) {
  const float* x     = (const float*)d_in[0];
  const float* Wq    = (const float*)d_in[1];
  const float* bq    = (const float*)d_in[2];
  const float* Wk    = (const float*)d_in[3];
  const float* bk    = (const float*)d_in[4];
  const float* Wv    = (const float*)d_in[5];
  const float* bv    = (const float*)d_in[6];
  const float* gamma = (const float*)d_in[7];
  float* out = (float*)d_out;

  char* ws = (char*)d_ws;
  float*    sig   = (float*)ws;                       // 4 floats
  unsigned* maxKu = (unsigned*)(ws + 16);             // 2 uints
  _Float16* K16   = (_Float16*)(ws + 10752);          // 294912 B
  _Float16* Q16   = (_Float16*)(ws + 10752 + 294912); // 294912 B
  _Float16* VT16  = (_Float16*)(ws + 10752 + 2 * 294912); // 2359296 B
  float*    Opart = (float*)(ws + 2960384);           // 1152*2048*4 = 9437184 B
  float*    Lpart = (float*)(ws + 2960384 + 9437184); // 1152*32*4 = 147456 B

  hipLaunchKernelGGL(k_sigma, dim3(3), dim3(64), 0, stream, Wq, Wk, Wv, sig, maxKu);
  hipLaunchKernelGGL(k_fgh, dim3(288), dim3(256), 0, stream,
                     x, Wq, bq, Wk, bk, Wv, bv, sig, K16, Q16, VT16, maxKu);
  hipLaunchKernelGGL(k_attn, dim3(1152), dim3(256), 0, stream, K16, Q16, VT16, maxKu, Opart, Lpart);
  hipLaunchKernelGGL(k_merge, dim3(576), dim3(256), 0, stream, Opart, Lpart, x, gamma, out);
}